// Round 4
// baseline (340.422 us; speedup 1.0000x reference)
//
#include <hip/hip_runtime.h>
#include <hip/hip_fp16.h>

#define NEG_SLOPE 0.1f
__device__ __forceinline__ float lrelu(float v) { return fmaxf(v, NEG_SLOPE * v); }

constexpr int CAP = 8704;   // per-bucket capacity (mean 6330 + 24-align pads); == 17*512
constexpr int EPB = 8192;   // edges per bin block (16 per thread, 512 threads)

typedef __attribute__((ext_vector_type(8))) short short8;   // 8 bf16 (4 VGPRs)
typedef __attribute__((ext_vector_type(4))) float f32x4;    // MFMA accum

__device__ __forceinline__ unsigned short f2bf(float f) {   // RNE
    union { float f; unsigned u; } v; v.f = f;
    const unsigned r = v.u + 0x7FFF + ((v.u >> 16) & 1);
    return (unsigned short)(r >> 16);
}
__device__ __forceinline__ float bf2f(unsigned short h) {
    union { unsigned u; float f; } v; v.u = ((unsigned)h) << 16;
    return v.f;
}

// ---------------------------------------------------------------------------
// Encoder (+fused prep in blocks 0..255): 4 nodes per 256-thread block,
// 12 KB LDS (high occupancy — do NOT fuse with bin: its 60 KB LDS halves
// encoder occupancy, measured +22 µs in r13). Prep: bf16 weight conversions,
// Wg build, gcur zero, xh sentinel row.
// ---------------------------------------------------------------------------
__global__ __launch_bounds__(256) void encoder_kernel(
        const float* __restrict__ pose,
        const float* __restrict__ views,
        const float* __restrict__ w1, const float* __restrict__ b1,
        const float* __restrict__ w2, const float* __restrict__ b2,
        const float* __restrict__ w_l1, const float* __restrict__ w_l2,
        const float* __restrict__ w_l3, const float* __restrict__ w_rel,
        const float* __restrict__ w_root,
        unsigned short* __restrict__ Wb1, unsigned short* __restrict__ Wb2,
        unsigned short* __restrict__ Wb3, unsigned short* __restrict__ Wg,
        int* __restrict__ gcur,
        unsigned short* __restrict__ xHi, unsigned short* __restrict__ xLo,
        __half* __restrict__ xh, int N)
{
    __shared__ float s_w1[81];
    __shared__ float s_b1[9];
    __shared__ float s_w2[27];
    __shared__ float s_b2[1];
    __shared__ float s_c1[4][9][80];   // [lnode][oc][(p&1)*40 + (p>>1)]

    const int t = threadIdx.x;

    // fused prep (first 256 blocks); runs before bin in stream order
    if (blockIdx.x < 256) {
        const int i = blockIdx.x * 256 + t;
        Wb1[i] = f2bf(w_l1[i]);
        Wb2[i] = f2bf(w_l2[i]);
        Wb3[i] = f2bf(w_l3[i]);
        if (i < 40960) {   // Wg[256][160] = [w_rel|w_root|w_rel|w_root]
            const int m = i / 160, c = i % 160;
            const int k = c % 80;
            const float v = (k < 40) ? w_rel[m * 40 + k] : w_root[m * 40 + (k - 40)];
            Wg[i] = f2bf(v);
        }
        if (i < 1024) gcur[i] = 0;
        if (i < 40) xh[(size_t)N * 40 + i] = __float2half(0.f);
    }

    if (t < 81) s_w1[t] = w1[t];
    if (t >= 96 && t < 105) s_b1[t - 96] = b1[t - 96];
    if (t >= 128 && t < 155) s_w2[t - 128] = w2[t - 128];
    if (t == 240) s_b2[0] = b2[0];
    __syncthreads();

    const int nb = blockIdx.x * 4;

    // conv1: 300 flat (node,pos) tasks over 2 passes (pass 2: waves 1-3 execz)
    #pragma unroll
    for (int pass = 0; pass < 2; pass++) {
        const int task = pass * 256 + t;
        if (task < 300) {
            const int ln = task / 75;
            const int p  = task % 75;
            const int n  = min(nb + ln, N - 1);
            const float* __restrict__ vin = views + (size_t)n * 453 + 2 * p;
            float e[3], o[3], e1[3];
            #pragma unroll
            for (int ic = 0; ic < 3; ic++) {
                const float* ci = vin + ic * 151;
                e[ic] = ci[0]; o[ic] = ci[1]; e1[ic] = ci[2];
            }
            const int didx = (p & 1) * 40 + (p >> 1);
            #pragma unroll
            for (int oc = 0; oc < 9; oc++) {
                float v = s_b1[oc];
                #pragma unroll
                for (int ic = 0; ic < 3; ic++)
                    v += s_w1[oc * 9 + ic * 3 + 0] * e[ic]
                       + s_w1[oc * 9 + ic * 3 + 1] * o[ic]
                       + s_w1[oc * 9 + ic * 3 + 2] * e1[ic];
                s_c1[ln][oc][didx] = lrelu(v);
            }
        }
    }
    __syncthreads();

    // conv2 + pose passthrough: 160 flat tasks, coalesced stores
    if (t < 160) {
        const int ln = t / 40, f = t % 40;
        const int n  = min(nb + ln, N - 1);
        float outv;
        if (f < 3) {
            outv = pose[(size_t)n * 3 + f];
        } else {
            const int ow = f - 3;
            float v = s_b2[0];
            #pragma unroll
            for (int ic = 0; ic < 9; ic++)
                v += s_w2[ic * 3 + 0] * s_c1[ln][ic][ow]
                   + s_w2[ic * 3 + 1] * s_c1[ln][ic][40 + ow]
                   + s_w2[ic * 3 + 2] * s_c1[ln][ic][ow + 1];
            outv = lrelu(v);
        }
        const unsigned short hi = f2bf(outv);
        const unsigned short lo = f2bf(outv - bf2f(hi));
        xHi[(size_t)n * 40 + f] = hi;
        xLo[(size_t)n * 40 + f] = lo;
        xh[(size_t)n * 40 + f] = __float2half(outv);
    }
}

// ---------------------------------------------------------------------------
// Coarse binning (512 thr, 8192 edges/block): rank via LDS histogram, stage
// bucket-ordered in LDS, linear write-out. Packed entry = src*80 | dloc<<22.
// ---------------------------------------------------------------------------
__global__ __launch_bounds__(512) void bin_kernel(
        const int* __restrict__ ei, int* __restrict__ gcur,
        int* __restrict__ pairs, int E, int NB)
{
    __shared__ int s_hist[1024];
    __shared__ int s_loff[1024];
    __shared__ int s_base[1024];
    __shared__ int s_wave8[8];
    __shared__ int s_pk[EPB];                 // 32 KB
    __shared__ unsigned short s_bkt[EPB];     // 16 KB
    const int t = threadIdx.x;
    const int lane = t & 63, wid = t >> 6;    // 8 waves
    const int e0 = blockIdx.x * EPB + t * 16;
    const int tot = min(E - (int)blockIdx.x * EPB, EPB);

    for (int i = t; i < 1024; i += 512) s_hist[i] = 0;
    __syncthreads();

    int pk[16], mt[16];
    auto proc = [&](int j, int sv, int dv) {
        const int b = dv >> 6;
        const int r = atomicAdd(&s_hist[b], 1);
        pk[j] = sv * 80 | ((dv & 63) << 22);
        mt[j] = b | (r << 10);
    };

    if (e0 + 16 <= E) {
        #pragma unroll
        for (int q = 0; q < 4; q++) {
            const int4 sv = *(const int4*)(ei + e0 + 4 * q);
            const int4 dv = *(const int4*)(ei + E + e0 + 4 * q);
            proc(4 * q + 0, sv.x, dv.x);
            proc(4 * q + 1, sv.y, dv.y);
            proc(4 * q + 2, sv.z, dv.z);
            proc(4 * q + 3, sv.w, dv.w);
        }
    } else {
        #pragma unroll
        for (int j = 0; j < 16; j++) {
            mt[j] = -1;
            const int e = e0 + j;
            if (e < E) proc(j, ei[e], ei[E + e]);
        }
    }
    __syncthreads();

    // exclusive scan of s_hist[0..1023] -> s_loff
    int carry = 0;
    #pragma unroll
    for (int base = 0; base < 1024; base += 512) {
        const int i = base + t;
        const int v = s_hist[i];
        int sc = v;
        #pragma unroll
        for (int d = 1; d < 64; d <<= 1) {
            const int u = __shfl_up(sc, d);
            if (lane >= d) sc += u;
        }
        if (lane == 63) s_wave8[wid] = sc;
        __syncthreads();
        if (wid == 0) {
            int wv = (lane < 8) ? s_wave8[lane] : 0;
            #pragma unroll
            for (int d = 1; d < 8; d <<= 1) {
                const int u = __shfl_up(wv, d);
                if (lane >= d) wv += u;
            }
            if (lane < 8) s_wave8[lane] = wv;
        }
        __syncthreads();
        const int waveoff = (wid > 0) ? s_wave8[wid - 1] : 0;
        s_loff[i] = carry + waveoff + sc - v;
        const int chunk_tot = s_wave8[7];
        __syncthreads();
        carry += chunk_tot;
    }

    for (int i = t; i < NB; i += 512) {
        const int c = s_hist[i];
        if (c > 0) s_base[i] = atomicAdd(&gcur[i], c);
    }
    __syncthreads();

    #pragma unroll
    for (int j = 0; j < 16; j++) {
        if (mt[j] >= 0) {
            const int b = mt[j] & 1023;
            const int pos = s_loff[b] + (mt[j] >> 10);
            s_pk[pos] = pk[j];
            s_bkt[pos] = (unsigned short)b;
        }
    }
    __syncthreads();

    for (int i = t; i < tot; i += 512) {
        const int b = s_bkt[i];
        const int p = s_base[b] + (i - s_loff[b]);
        if (p < CAP) pairs[b * CAP + p] = s_pk[i];
    }
}

// ---------------------------------------------------------------------------
// FUSED per-bucket sort + gather (512 thr, one block per bucket): counting
// sort scatters byte-offset edges into an LDS sorted list (runs 24-aligned,
// sentinel N*80 = zero row), then 8 waves gather 8 nodes each.
// r2: 16 B/lane gather (12 slots x 5 lanes) — TA-address-bound fix, -8 µs.
// ---------------------------------------------------------------------------
__global__ __launch_bounds__(512) void sort_gather_kernel(
        const int* __restrict__ gcur,
        const int* __restrict__ pairs,
        const __half* __restrict__ xh,
        unsigned short* __restrict__ aggHi,
        unsigned short* __restrict__ aggLo, int N)
{
    __shared__ int s_sorted[CAP];             // 34.8 KB
    __shared__ int s_cnt[64], s_off[64], s_cur[64];
    const int b = blockIdx.x;
    const int t = threadIdx.x;
    const int cnt = min(gcur[b], CAP);
    const int* __restrict__ pr = pairs + (size_t)b * CAP;

    if (t < 64) s_cnt[t] = 0;

    // stage this thread's packed entries in registers (single global read;
    // entries are always >= 0, sentinel -1 marks out-of-range slots)
    int pk[17];
    #pragma unroll
    for (int j = 0; j < 17; j++) {
        const int i = t + j * 512;
        pk[j] = (i < cnt) ? __builtin_nontemporal_load(pr + i) : -1;
    }
    __syncthreads();

    #pragma unroll
    for (int j = 0; j < 17; j++)
        if (pk[j] >= 0) atomicAdd(&s_cnt[pk[j] >> 22], 1);
    __syncthreads();

    if (t < 64) {   // wave 0: exclusive scan of 24-aligned counts
        const int c = s_cnt[t];
        const int p = ((c + 23) / 24) * 24;
        int sc = p;
        #pragma unroll
        for (int d = 1; d < 64; d <<= 1) {
            const int u = __shfl_up(sc, d);
            if (t >= d) sc += u;
        }
        const int excl = sc - p;
        s_off[t] = excl;
        s_cur[t] = excl;
    }
    __syncthreads();

    if (t < 64) {   // pad fill: sentinel byte offset N*80 (zero row in xh)
        const int e0 = s_off[t] + s_cnt[t];
        const int e1 = s_off[t] + ((s_cnt[t] + 23) / 24) * 24;
        for (int i = e0; i < e1 && i < CAP; i++) s_sorted[i] = N * 80;
    }
    #pragma unroll
    for (int j = 0; j < 17; j++) {
        if (pk[j] >= 0) {
            const int pos = atomicAdd(&s_cur[pk[j] >> 22], 1);
            if (pos < CAP) s_sorted[pos] = pk[j] & 0x3FFFFF;
        }
    }
    __syncthreads();

    // gather: wave w handles local nodes w*8 .. w*8+7.
    // 12 slots x 5 lanes; each lane loads 16 B (8 halfs) of its slot's row.
    const int wave = t >> 6, lane = t & 63;
    const int slot = min(lane / 5, 11);       // lanes 60..63 duplicate slot 11
    const int f8 = lane % 5;                  // feature octet (8 halfs = 16 B)
    const char* __restrict__ xb = (const char*)xh + f8 * 16;

    #pragma unroll 1
    for (int i = 0; i < 8; i++) {
        const int ln = wave * 8 + i;
        const int n = b * 64 + ln;
        if (n >= N) break;                    // wave-uniform
        const int c = s_cnt[ln];
        const int cntp = ((c + 23) / 24) * 24;
        const int* __restrict__ srt = s_sorted + s_off[ln] + slot;

        float a[8];
        #pragma unroll
        for (int j = 0; j < 8; j++) a[j] = 0.f;

        union { unsigned v; __half2 h; } cv;
        float2 f;
        auto acc8 = [&](uint4 u) {
            cv.v = u.x; f = __half22float2(cv.h); a[0] += f.x; a[1] += f.y;
            cv.v = u.y; f = __half22float2(cv.h); a[2] += f.x; a[3] += f.y;
            cv.v = u.z; f = __half22float2(cv.h); a[4] += f.x; a[5] += f.y;
            cv.v = u.w; f = __half22float2(cv.h); a[6] += f.x; a[7] += f.y;
        };

        int e = 0;
        #pragma unroll 1
        for (; e + 48 <= cntp; e += 48) {     // 4 x 16B loads in flight
            const int o0 = srt[e];
            const int o1 = srt[e + 12];
            const int o2 = srt[e + 24];
            const int o3 = srt[e + 36];
            const uint4 u0 = *(const uint4*)(xb + o0);
            const uint4 u1 = *(const uint4*)(xb + o1);
            const uint4 u2 = *(const uint4*)(xb + o2);
            const uint4 u3 = *(const uint4*)(xb + o3);
            acc8(u0); acc8(u1); acc8(u2); acc8(u3);
        }
        if (e < cntp) {                       // tail: exactly one 24-chunk
            const int o0 = srt[e];
            const int o1 = srt[e + 12];
            const uint4 u0 = *(const uint4*)(xb + o0);
            const uint4 u1 = *(const uint4*)(xb + o1);
            acc8(u0); acc8(u1);
        }

        // fold 12 slots -> slot 0 (lanes 0..4); deltas preserve f8 (==0 mod 5)
        #pragma unroll
        for (int j = 0; j < 8; j++) a[j] += __shfl(a[j], lane + 30);
        #pragma unroll
        for (int j = 0; j < 8; j++) a[j] += __shfl(a[j], lane + 15);
        #pragma unroll
        for (int j = 0; j < 8; j++) a[j] += __shfl(a[j], lane + 5) + __shfl(a[j], lane + 10);

        if (lane < 5) {
            unsigned short h[8], l[8];
            #pragma unroll
            for (int j = 0; j < 8; j++) {
                h[j] = f2bf(a[j]);
                l[j] = f2bf(a[j] - bf2f(h[j]));
            }
            uint4 H, L;
            H.x = h[0] | ((unsigned)h[1] << 16); H.y = h[2] | ((unsigned)h[3] << 16);
            H.z = h[4] | ((unsigned)h[5] << 16); H.w = h[6] | ((unsigned)h[7] << 16);
            L.x = l[0] | ((unsigned)l[1] << 16); L.y = l[2] | ((unsigned)l[3] << 16);
            L.z = l[4] | ((unsigned)l[5] << 16); L.w = l[6] | ((unsigned)l[7] << 16);
            *(uint4*)(aggHi + (size_t)n * 40 + lane * 8) = H;
            *(uint4*)(aggLo + (size_t)n * 40 + lane * 8) = L;
        }
    }
}

// ---------------------------------------------------------------------------
// FUSED GEMM chain: graphconv (K=160) -> mlp1 -> mlp2 -> mlp3+pred, one
// block per 64 rows; h stays in LDS between layers.
// r3: explicit ping-pong double-buffer of af/wf across k-steps + launch_bounds
// (256,4) (VGPR cap 64->128). Was latency-bound: VGPR=64 forced the compiler
// to serialize the ~250-cyc L2 wf load into every k-step (MfmaUtil 14%,
// VALUBusy 15%, occ 27% — all low).
// ---------------------------------------------------------------------------
__device__ __forceinline__ void gemm_tile(const unsigned short* __restrict__ aT,
                                          const unsigned short* __restrict__ W,
                                          int wstride, int K,
                                          int wave, int l16, int q,
                                          f32x4 acc[4][4])
{
    const unsigned short* __restrict__ ap = aT + l16 * 264 + q * 8;
    const unsigned short* __restrict__ wp = W + (wave * 64 + l16) * wstride + q * 8;

    short8 afA[4], wfA[4], afB[4], wfB[4];
    #pragma unroll
    for (int nt = 0; nt < 4; nt++) afA[nt] = *(const short8*)(ap + nt * 16 * 264);
    #pragma unroll
    for (int mt = 0; mt < 4; mt++) wfA[mt] = *(const short8*)(wp + mt * 16 * wstride);

    for (int k0 = 0; k0 + 64 <= K; k0 += 64) {
        #pragma unroll
        for (int nt = 0; nt < 4; nt++) afB[nt] = *(const short8*)(ap + nt * 16 * 264 + k0 + 32);
        #pragma unroll
        for (int mt = 0; mt < 4; mt++) wfB[mt] = *(const short8*)(wp + mt * 16 * wstride + k0 + 32);
        #pragma unroll
        for (int nt = 0; nt < 4; nt++)
            #pragma unroll
            for (int mt = 0; mt < 4; mt++)
                acc[nt][mt] = __builtin_amdgcn_mfma_f32_16x16x32_bf16(afA[nt], wfA[mt], acc[nt][mt], 0, 0, 0);
        if (k0 + 64 < K) {
            #pragma unroll
            for (int nt = 0; nt < 4; nt++) afA[nt] = *(const short8*)(ap + nt * 16 * 264 + k0 + 64);
            #pragma unroll
            for (int mt = 0; mt < 4; mt++) wfA[mt] = *(const short8*)(wp + mt * 16 * wstride + k0 + 64);
        }
        #pragma unroll
        for (int nt = 0; nt < 4; nt++)
            #pragma unroll
            for (int mt = 0; mt < 4; mt++)
                acc[nt][mt] = __builtin_amdgcn_mfma_f32_16x16x32_bf16(afB[nt], wfB[mt], acc[nt][mt], 0, 0, 0);
    }
    if (K & 32) {   // odd k-step count (K=160): last 32 already resident in A
        #pragma unroll
        for (int nt = 0; nt < 4; nt++)
            #pragma unroll
            for (int mt = 0; mt < 4; mt++)
                acc[nt][mt] = __builtin_amdgcn_mfma_f32_16x16x32_bf16(afA[nt], wfA[mt], acc[nt][mt], 0, 0, 0);
    }
}

__device__ __forceinline__ void epi_to_lds(f32x4 acc[4][4], const float* __restrict__ b,
                                           unsigned short* __restrict__ aT,
                                           int wave, int l16, int q)
{
    float bias[4];
    #pragma unroll
    for (int mt = 0; mt < 4; mt++) bias[mt] = b[wave * 64 + mt * 16 + l16];
    #pragma unroll
    for (int nt = 0; nt < 4; nt++)
        #pragma unroll
        for (int r = 0; r < 4; r++)
            #pragma unroll
            for (int mt = 0; mt < 4; mt++) {
                const int row = nt * 16 + q * 4 + r;         // C/D: row=quad*4+reg
                const int col = wave * 64 + mt * 16 + l16;   // C/D: col=lane&15
                aT[row * 264 + col] = f2bf(lrelu(acc[nt][mt][r] + bias[mt]));
            }
}

__global__ __launch_bounds__(256, 4) void fused_gemm_kernel(
                                  const unsigned short* __restrict__ aggHi,
                                  const unsigned short* __restrict__ aggLo,
                                  const unsigned short* __restrict__ xHi,
                                  const unsigned short* __restrict__ xLo,
                                  const unsigned short* __restrict__ Wg,
                                  const float* __restrict__ b_rel,
                                  const unsigned short* __restrict__ Wb1,
                                  const float* __restrict__ b_l1,
                                  const unsigned short* __restrict__ Wb2,
                                  const float* __restrict__ b_l2,
                                  const unsigned short* __restrict__ Wb3,
                                  const float* __restrict__ b_l3,
                                  const float* __restrict__ w_pred,
                                  const float* __restrict__ b_pred,
                                  float* __restrict__ out, int N)
{
    __shared__ __align__(16) unsigned short aT[64 * 264];   // 33 KB, reused per layer
    __shared__ float s_part[4][64];
    const int t = threadIdx.x;
    const int n0 = blockIdx.x * 64;
    const int wave = t >> 6, lane = t & 63, q = lane >> 4, l16 = lane & 15;

    for (int u = t; u < 640; u += 256) {
        const int row = u / 10, c = (u % 10) * 4;
        const int srow = min(n0 + row, N - 1);
        const size_t off = (size_t)srow * 40 + c;
        unsigned short* rp = aT + row * 264;
        *(ushort4*)(rp + c)       = *(const ushort4*)(aggHi + off);
        *(ushort4*)(rp + 40 + c)  = *(const ushort4*)(xHi + off);
        *(ushort4*)(rp + 80 + c)  = *(const ushort4*)(aggLo + off);
        *(ushort4*)(rp + 120 + c) = *(const ushort4*)(xLo + off);
    }
    __syncthreads();

    {   // layer 0: graphconv, K=160
        f32x4 acc[4][4] = {};
        gemm_tile(aT, Wg, 160, 160, wave, l16, q, acc);
        __syncthreads();
        epi_to_lds(acc, b_rel, aT, wave, l16, q);
        __syncthreads();
    }
    {   // layer 1
        f32x4 acc[4][4] = {};
        gemm_tile(aT, Wb1, 256, 256, wave, l16, q, acc);
        __syncthreads();
        epi_to_lds(acc, b_l1, aT, wave, l16, q);
        __syncthreads();
    }
    {   // layer 2
        f32x4 acc[4][4] = {};
        gemm_tile(aT, Wb2, 256, 256, wave, l16, q, acc);
        __syncthreads();
        epi_to_lds(acc, b_l2, aT, wave, l16, q);
        __syncthreads();
    }
    {   // layer 3 + pred epilogue (h3 never leaves registers)
        f32x4 acc[4][4] = {};
        gemm_tile(aT, Wb3, 256, 256, wave, l16, q, acc);

        float bias[4], wp[4];
        #pragma unroll
        for (int mt = 0; mt < 4; mt++) {
            const int col = wave * 64 + mt * 16 + l16;
            bias[mt] = b_l3[col];
            wp[mt] = w_pred[col];
        }
        #pragma unroll
        for (int nt = 0; nt < 4; nt++)
            #pragma unroll
            for (int r = 0; r < 4; r++) {
                float p = 0.f;
                #pragma unroll
                for (int mt = 0; mt < 4; mt++)
                    p += lrelu(acc[nt][mt][r] + bias[mt]) * wp[mt];
                p += __shfl_xor(p, 1);
                p += __shfl_xor(p, 2);
                p += __shfl_xor(p, 4);
                p += __shfl_xor(p, 8);
                if (l16 == 0) s_part[wave][nt * 16 + q * 4 + r] = p;
            }
        __syncthreads();

        if (t < 64) {
            const int row = n0 + t;
            if (row < N)
                out[row] = s_part[0][t] + s_part[1][t] + s_part[2][t] + s_part[3][t] + b_pred[0];
        }
    }
}

// ---------------------------------------------------------------------------
extern "C" void kernel_launch(void* const* d_in, const int* in_sizes, int n_in,
                              void* d_out, int out_size, void* d_ws, size_t ws_size,
                              hipStream_t stream)
{
    const float* pose   = (const float*)d_in[0];
    const float* views  = (const float*)d_in[1];
    const int*   ei     = (const int*)d_in[2];
    const float* w_e1   = (const float*)d_in[3];
    const float* b_e1   = (const float*)d_in[4];
    const float* w_e2   = (const float*)d_in[5];
    const float* b_e2   = (const float*)d_in[6];
    const float* w_rel  = (const float*)d_in[7];
    const float* b_rel  = (const float*)d_in[8];
    const float* w_root = (const float*)d_in[9];
    const float* w_l1   = (const float*)d_in[10];
    const float* b_l1   = (const float*)d_in[11];
    const float* w_l2   = (const float*)d_in[12];
    const float* b_l2   = (const float*)d_in[13];
    const float* w_l3   = (const float*)d_in[14];
    const float* b_l3   = (const float*)d_in[15];
    const float* w_pred = (const float*)d_in[16];
    const float* b_pred = (const float*)d_in[17];
    float* out = (float*)d_out;

    const int N = in_sizes[0] / 3;        // 50000
    const int E = in_sizes[2] / 2;        // 4950000
    const int NB = (N + 63) >> 6;         // 782 buckets
    const int NBLK = (N + 63) / 64;       // 782 GEMM row blocks

    // Workspace layout (no sorted / node_start / node_cnt / h buffers)
    unsigned short* xHi = (unsigned short*)d_ws;     // N*40 bf16
    unsigned short* xLo = xHi + (size_t)N * 40;      // N*40 bf16
    unsigned short* aggHi = xLo + (size_t)N * 40;    // N*40 bf16
    unsigned short* aggLo = aggHi + (size_t)N * 40;  // N*40 bf16
    __half* xh = (__half*)(aggLo + (size_t)N * 40);  // (N+1)*40 fp16; row N = 0
    int* pairs = (int*)(xh + (size_t)(N + 1) * 40 + 24);   // NB*CAP ints
    int* gcur  = pairs + (size_t)NB * CAP;           // 1024
    unsigned short* Wb1 = (unsigned short*)(gcur + 1024);  // 256*256
    unsigned short* Wb2 = Wb1 + 256 * 256;
    unsigned short* Wb3 = Wb2 + 256 * 256;
    unsigned short* Wg  = Wb3 + 256 * 256;           // 256*160

    encoder_kernel<<<(N + 3) / 4, 256, 0, stream>>>(
        pose, views, w_e1, b_e1, w_e2, b_e2,
        w_l1, w_l2, w_l3, w_rel, w_root,
        Wb1, Wb2, Wb3, Wg, gcur, xHi, xLo, xh, N);

    bin_kernel<<<(E + EPB - 1) / EPB, 512, 0, stream>>>(ei, gcur, pairs, E, NB);

    sort_gather_kernel<<<NB, 512, 0, stream>>>(gcur, pairs, xh, aggHi, aggLo, N);

    fused_gemm_kernel<<<NBLK, 256, 0, stream>>>(
        aggHi, aggLo, xHi, xLo, Wg, b_rel,
        Wb1, b_l1, Wb2, b_l2, Wb3, b_l3,
        w_pred, b_pred, out, N);
}

// Round 5
// 326.914 us; speedup vs baseline: 1.0413x; 1.0413x over previous
//
#include <hip/hip_runtime.h>
#include <hip/hip_fp16.h>

#define NEG_SLOPE 0.1f
__device__ __forceinline__ float lrelu(float v) { return fmaxf(v, NEG_SLOPE * v); }

constexpr int CAP = 8704;   // per-bucket capacity (mean 6330 + 24-align pads); == 17*512
constexpr int EPB = 8192;   // edges per bin block (16 per thread, 512 threads)

typedef __attribute__((ext_vector_type(8))) short short8;   // 8 bf16 (4 VGPRs)
typedef __attribute__((ext_vector_type(4))) float f32x4;    // MFMA accum

__device__ __forceinline__ unsigned short f2bf(float f) {   // RNE
    union { float f; unsigned u; } v; v.f = f;
    const unsigned r = v.u + 0x7FFF + ((v.u >> 16) & 1);
    return (unsigned short)(r >> 16);
}
__device__ __forceinline__ float bf2f(unsigned short h) {
    union { unsigned u; float f; } v; v.u = ((unsigned)h) << 16;
    return v.f;
}

// ---------------------------------------------------------------------------
// Encoder (+fused prep in blocks 0..255): 4 nodes per 256-thread block,
// 12 KB LDS (high occupancy — do NOT fuse with bin: its 60 KB LDS halves
// encoder occupancy, measured +22 µs in r13). Prep: bf16 weight conversions,
// Wg build, gcur zero, xh sentinel row.
// ---------------------------------------------------------------------------
__global__ __launch_bounds__(256) void encoder_kernel(
        const float* __restrict__ pose,
        const float* __restrict__ views,
        const float* __restrict__ w1, const float* __restrict__ b1,
        const float* __restrict__ w2, const float* __restrict__ b2,
        const float* __restrict__ w_l1, const float* __restrict__ w_l2,
        const float* __restrict__ w_l3, const float* __restrict__ w_rel,
        const float* __restrict__ w_root,
        unsigned short* __restrict__ Wb1, unsigned short* __restrict__ Wb2,
        unsigned short* __restrict__ Wb3, unsigned short* __restrict__ Wg,
        int* __restrict__ gcur,
        unsigned short* __restrict__ xHi, unsigned short* __restrict__ xLo,
        __half* __restrict__ xh, int N)
{
    __shared__ float s_w1[81];
    __shared__ float s_b1[9];
    __shared__ float s_w2[27];
    __shared__ float s_b2[1];
    __shared__ float s_c1[4][9][80];   // [lnode][oc][(p&1)*40 + (p>>1)]

    const int t = threadIdx.x;

    // fused prep (first 256 blocks); runs before bin in stream order
    if (blockIdx.x < 256) {
        const int i = blockIdx.x * 256 + t;
        Wb1[i] = f2bf(w_l1[i]);
        Wb2[i] = f2bf(w_l2[i]);
        Wb3[i] = f2bf(w_l3[i]);
        if (i < 40960) {   // Wg[256][160] = [w_rel|w_root|w_rel|w_root]
            const int m = i / 160, c = i % 160;
            const int k = c % 80;
            const float v = (k < 40) ? w_rel[m * 40 + k] : w_root[m * 40 + (k - 40)];
            Wg[i] = f2bf(v);
        }
        if (i < 1024) gcur[i] = 0;
        if (i < 40) xh[(size_t)N * 40 + i] = __float2half(0.f);
    }

    if (t < 81) s_w1[t] = w1[t];
    if (t >= 96 && t < 105) s_b1[t - 96] = b1[t - 96];
    if (t >= 128 && t < 155) s_w2[t - 128] = w2[t - 128];
    if (t == 240) s_b2[0] = b2[0];
    __syncthreads();

    const int nb = blockIdx.x * 4;

    // conv1: 300 flat (node,pos) tasks over 2 passes (pass 2: waves 1-3 execz)
    #pragma unroll
    for (int pass = 0; pass < 2; pass++) {
        const int task = pass * 256 + t;
        if (task < 300) {
            const int ln = task / 75;
            const int p  = task % 75;
            const int n  = min(nb + ln, N - 1);
            const float* __restrict__ vin = views + (size_t)n * 453 + 2 * p;
            float e[3], o[3], e1[3];
            #pragma unroll
            for (int ic = 0; ic < 3; ic++) {
                const float* ci = vin + ic * 151;
                e[ic] = ci[0]; o[ic] = ci[1]; e1[ic] = ci[2];
            }
            const int didx = (p & 1) * 40 + (p >> 1);
            #pragma unroll
            for (int oc = 0; oc < 9; oc++) {
                float v = s_b1[oc];
                #pragma unroll
                for (int ic = 0; ic < 3; ic++)
                    v += s_w1[oc * 9 + ic * 3 + 0] * e[ic]
                       + s_w1[oc * 9 + ic * 3 + 1] * o[ic]
                       + s_w1[oc * 9 + ic * 3 + 2] * e1[ic];
                s_c1[ln][oc][didx] = lrelu(v);
            }
        }
    }
    __syncthreads();

    // conv2 + pose passthrough: 160 flat tasks, coalesced stores
    if (t < 160) {
        const int ln = t / 40, f = t % 40;
        const int n  = min(nb + ln, N - 1);
        float outv;
        if (f < 3) {
            outv = pose[(size_t)n * 3 + f];
        } else {
            const int ow = f - 3;
            float v = s_b2[0];
            #pragma unroll
            for (int ic = 0; ic < 9; ic++)
                v += s_w2[ic * 3 + 0] * s_c1[ln][ic][ow]
                   + s_w2[ic * 3 + 1] * s_c1[ln][ic][40 + ow]
                   + s_w2[ic * 3 + 2] * s_c1[ln][ic][ow + 1];
            outv = lrelu(v);
        }
        const unsigned short hi = f2bf(outv);
        const unsigned short lo = f2bf(outv - bf2f(hi));
        xHi[(size_t)n * 40 + f] = hi;
        xLo[(size_t)n * 40 + f] = lo;
        xh[(size_t)n * 40 + f] = __float2half(outv);
    }
}

// ---------------------------------------------------------------------------
// Coarse binning (512 thr, 8192 edges/block): rank via LDS histogram, stage
// bucket-ordered in LDS, linear write-out. Packed entry = src*80 | dloc<<22.
// ---------------------------------------------------------------------------
__global__ __launch_bounds__(512) void bin_kernel(
        const int* __restrict__ ei, int* __restrict__ gcur,
        int* __restrict__ pairs, int E, int NB)
{
    __shared__ int s_hist[1024];
    __shared__ int s_loff[1024];
    __shared__ int s_base[1024];
    __shared__ int s_wave8[8];
    __shared__ int s_pk[EPB];                 // 32 KB
    __shared__ unsigned short s_bkt[EPB];     // 16 KB
    const int t = threadIdx.x;
    const int lane = t & 63, wid = t >> 6;    // 8 waves
    const int e0 = blockIdx.x * EPB + t * 16;
    const int tot = min(E - (int)blockIdx.x * EPB, EPB);

    for (int i = t; i < 1024; i += 512) s_hist[i] = 0;
    __syncthreads();

    int pk[16], mt[16];
    auto proc = [&](int j, int sv, int dv) {
        const int b = dv >> 6;
        const int r = atomicAdd(&s_hist[b], 1);
        pk[j] = sv * 80 | ((dv & 63) << 22);
        mt[j] = b | (r << 10);
    };

    if (e0 + 16 <= E) {
        #pragma unroll
        for (int q = 0; q < 4; q++) {
            const int4 sv = *(const int4*)(ei + e0 + 4 * q);
            const int4 dv = *(const int4*)(ei + E + e0 + 4 * q);
            proc(4 * q + 0, sv.x, dv.x);
            proc(4 * q + 1, sv.y, dv.y);
            proc(4 * q + 2, sv.z, dv.z);
            proc(4 * q + 3, sv.w, dv.w);
        }
    } else {
        #pragma unroll
        for (int j = 0; j < 16; j++) {
            mt[j] = -1;
            const int e = e0 + j;
            if (e < E) proc(j, ei[e], ei[E + e]);
        }
    }
    __syncthreads();

    // exclusive scan of s_hist[0..1023] -> s_loff
    int carry = 0;
    #pragma unroll
    for (int base = 0; base < 1024; base += 512) {
        const int i = base + t;
        const int v = s_hist[i];
        int sc = v;
        #pragma unroll
        for (int d = 1; d < 64; d <<= 1) {
            const int u = __shfl_up(sc, d);
            if (lane >= d) sc += u;
        }
        if (lane == 63) s_wave8[wid] = sc;
        __syncthreads();
        if (wid == 0) {
            int wv = (lane < 8) ? s_wave8[lane] : 0;
            #pragma unroll
            for (int d = 1; d < 8; d <<= 1) {
                const int u = __shfl_up(wv, d);
                if (lane >= d) wv += u;
            }
            if (lane < 8) s_wave8[lane] = wv;
        }
        __syncthreads();
        const int waveoff = (wid > 0) ? s_wave8[wid - 1] : 0;
        s_loff[i] = carry + waveoff + sc - v;
        const int chunk_tot = s_wave8[7];
        __syncthreads();
        carry += chunk_tot;
    }

    for (int i = t; i < NB; i += 512) {
        const int c = s_hist[i];
        if (c > 0) s_base[i] = atomicAdd(&gcur[i], c);
    }
    __syncthreads();

    #pragma unroll
    for (int j = 0; j < 16; j++) {
        if (mt[j] >= 0) {
            const int b = mt[j] & 1023;
            const int pos = s_loff[b] + (mt[j] >> 10);
            s_pk[pos] = pk[j];
            s_bkt[pos] = (unsigned short)b;
        }
    }
    __syncthreads();

    for (int i = t; i < tot; i += 512) {
        const int b = s_bkt[i];
        const int p = s_base[b] + (i - s_loff[b]);
        if (p < CAP) pairs[b * CAP + p] = s_pk[i];
    }
}

// ---------------------------------------------------------------------------
// FUSED per-bucket sort + gather (512 thr, one block per bucket): counting
// sort scatters byte-offset edges into an LDS sorted list (runs 24-aligned,
// sentinel N*80 = zero row), then 8 waves gather 8 nodes each.
// r2: 16 B/lane gather (12 slots x 5 lanes) — TA-address-bound fix, -8 µs.
// ---------------------------------------------------------------------------
__global__ __launch_bounds__(512) void sort_gather_kernel(
        const int* __restrict__ gcur,
        const int* __restrict__ pairs,
        const __half* __restrict__ xh,
        unsigned short* __restrict__ aggHi,
        unsigned short* __restrict__ aggLo, int N)
{
    __shared__ int s_sorted[CAP];             // 34.8 KB
    __shared__ int s_cnt[64], s_off[64], s_cur[64];
    const int b = blockIdx.x;
    const int t = threadIdx.x;
    const int cnt = min(gcur[b], CAP);
    const int* __restrict__ pr = pairs + (size_t)b * CAP;

    if (t < 64) s_cnt[t] = 0;

    // stage this thread's packed entries in registers (single global read;
    // entries are always >= 0, sentinel -1 marks out-of-range slots)
    int pk[17];
    #pragma unroll
    for (int j = 0; j < 17; j++) {
        const int i = t + j * 512;
        pk[j] = (i < cnt) ? __builtin_nontemporal_load(pr + i) : -1;
    }
    __syncthreads();

    #pragma unroll
    for (int j = 0; j < 17; j++)
        if (pk[j] >= 0) atomicAdd(&s_cnt[pk[j] >> 22], 1);
    __syncthreads();

    if (t < 64) {   // wave 0: exclusive scan of 24-aligned counts
        const int c = s_cnt[t];
        const int p = ((c + 23) / 24) * 24;
        int sc = p;
        #pragma unroll
        for (int d = 1; d < 64; d <<= 1) {
            const int u = __shfl_up(sc, d);
            if (t >= d) sc += u;
        }
        const int excl = sc - p;
        s_off[t] = excl;
        s_cur[t] = excl;
    }
    __syncthreads();

    if (t < 64) {   // pad fill: sentinel byte offset N*80 (zero row in xh)
        const int e0 = s_off[t] + s_cnt[t];
        const int e1 = s_off[t] + ((s_cnt[t] + 23) / 24) * 24;
        for (int i = e0; i < e1 && i < CAP; i++) s_sorted[i] = N * 80;
    }
    #pragma unroll
    for (int j = 0; j < 17; j++) {
        if (pk[j] >= 0) {
            const int pos = atomicAdd(&s_cur[pk[j] >> 22], 1);
            if (pos < CAP) s_sorted[pos] = pk[j] & 0x3FFFFF;
        }
    }
    __syncthreads();

    // gather: wave w handles local nodes w*8 .. w*8+7.
    // 12 slots x 5 lanes; each lane loads 16 B (8 halfs) of its slot's row.
    const int wave = t >> 6, lane = t & 63;
    const int slot = min(lane / 5, 11);       // lanes 60..63 duplicate slot 11
    const int f8 = lane % 5;                  // feature octet (8 halfs = 16 B)
    const char* __restrict__ xb = (const char*)xh + f8 * 16;

    #pragma unroll 1
    for (int i = 0; i < 8; i++) {
        const int ln = wave * 8 + i;
        const int n = b * 64 + ln;
        if (n >= N) break;                    // wave-uniform
        const int c = s_cnt[ln];
        const int cntp = ((c + 23) / 24) * 24;
        const int* __restrict__ srt = s_sorted + s_off[ln] + slot;

        float a[8];
        #pragma unroll
        for (int j = 0; j < 8; j++) a[j] = 0.f;

        union { unsigned v; __half2 h; } cv;
        float2 f;
        auto acc8 = [&](uint4 u) {
            cv.v = u.x; f = __half22float2(cv.h); a[0] += f.x; a[1] += f.y;
            cv.v = u.y; f = __half22float2(cv.h); a[2] += f.x; a[3] += f.y;
            cv.v = u.z; f = __half22float2(cv.h); a[4] += f.x; a[5] += f.y;
            cv.v = u.w; f = __half22float2(cv.h); a[6] += f.x; a[7] += f.y;
        };

        int e = 0;
        #pragma unroll 1
        for (; e + 48 <= cntp; e += 48) {     // 4 x 16B loads in flight
            const int o0 = srt[e];
            const int o1 = srt[e + 12];
            const int o2 = srt[e + 24];
            const int o3 = srt[e + 36];
            const uint4 u0 = *(const uint4*)(xb + o0);
            const uint4 u1 = *(const uint4*)(xb + o1);
            const uint4 u2 = *(const uint4*)(xb + o2);
            const uint4 u3 = *(const uint4*)(xb + o3);
            acc8(u0); acc8(u1); acc8(u2); acc8(u3);
        }
        if (e < cntp) {                       // tail: exactly one 24-chunk
            const int o0 = srt[e];
            const int o1 = srt[e + 12];
            const uint4 u0 = *(const uint4*)(xb + o0);
            const uint4 u1 = *(const uint4*)(xb + o1);
            acc8(u0); acc8(u1);
        }

        // fold 12 slots -> slot 0 (lanes 0..4); deltas preserve f8 (==0 mod 5)
        #pragma unroll
        for (int j = 0; j < 8; j++) a[j] += __shfl(a[j], lane + 30);
        #pragma unroll
        for (int j = 0; j < 8; j++) a[j] += __shfl(a[j], lane + 15);
        #pragma unroll
        for (int j = 0; j < 8; j++) a[j] += __shfl(a[j], lane + 5) + __shfl(a[j], lane + 10);

        if (lane < 5) {
            unsigned short h[8], l[8];
            #pragma unroll
            for (int j = 0; j < 8; j++) {
                h[j] = f2bf(a[j]);
                l[j] = f2bf(a[j] - bf2f(h[j]));
            }
            uint4 H, L;
            H.x = h[0] | ((unsigned)h[1] << 16); H.y = h[2] | ((unsigned)h[3] << 16);
            H.z = h[4] | ((unsigned)h[5] << 16); H.w = h[6] | ((unsigned)h[7] << 16);
            L.x = l[0] | ((unsigned)l[1] << 16); L.y = l[2] | ((unsigned)l[3] << 16);
            L.z = l[4] | ((unsigned)l[5] << 16); L.w = l[6] | ((unsigned)l[7] << 16);
            *(uint4*)(aggHi + (size_t)n * 40 + lane * 8) = H;
            *(uint4*)(aggLo + (size_t)n * 40 + lane * 8) = L;
        }
    }
}

// ---------------------------------------------------------------------------
// FUSED GEMM chain: graphconv (K=160) -> mlp1 -> mlp2 -> mlp3+pred, one
// block per 64 rows; h stays in LDS between layers.
// r5: W-panel LDS staging via async global_load_lds, double-buffered with
// counted vmcnt(4) (never 0 mid-loop). Each wave stages exactly the 64 W-rows
// it reads (chunk-private LDS) -> NO barriers in the k-loop; waves skew
// freely. wf latency 250cy L2 -> 12cy ds_read. aT re-laid at stride 256 with
// XOR swizzle col^((row&7)<<3) (kills 16-way bank alias; frees pad bytes);
// s_part folded into wave-private sW chunk -> LDS exactly 64 KB, 2 blocks/CU.
// r4 lesson: NO register double-buffer, NO launch_bounds min-waves (spilled:
// WRITE_SIZE 195KB->6.4MB).
// ---------------------------------------------------------------------------
__device__ __forceinline__ int aswz(int row, int col) {   // aT swizzled ushort idx
    return row * 256 + (col ^ ((row & 7) << 3));
}

__device__ __forceinline__ void gload16(const void* g, void* l) {
    __builtin_amdgcn_global_load_lds(
        (const __attribute__((address_space(1))) unsigned int*)g,
        (__attribute__((address_space(3))) unsigned int*)l,
        16, 0, 0);
}

// stage the wave's own 64 rows of W[*, k0..k0+32) into its private chunks
__device__ __forceinline__ void stage_panel(const unsigned short* __restrict__ W,
                                            int wstride, int k0,
                                            unsigned short* buf, int wave, int lane)
{
    const int rbase = wave * 64 + (lane >> 2);
    const int cu = (lane & 3) * 8;
    #pragma unroll
    for (int j = 0; j < 4; j++) {
        const int row = rbase + j * 16;
        gload16(W + (size_t)row * wstride + k0 + cu,
                buf + (wave * 4 + j) * 512);
    }
}

__device__ __forceinline__ void gemm_layer(const unsigned short* __restrict__ aT,
                                           const unsigned short* __restrict__ W,
                                           int wstride, int K,
                                           unsigned short* __restrict__ sW0,
                                           unsigned short* __restrict__ sW1,
                                           int wave, int lane, int l16, int q,
                                           f32x4 acc[4][4])
{
    const int NP = K >> 5;                    // 32-wide k panels
    stage_panel(W, wstride, 0, sW0, wave, lane);
    stage_panel(W, wstride, 32, sW1, wave, lane);
    const int wrow = (wave * 64 + l16) * 32 + q * 8;

    for (int p = 0; p < NP; p++) {
        unsigned short* wb = (p & 1) ? sW1 : sW0;
        // counted wait: oldest 4 outstanding (panel p) done; panel p+1 in flight
        if (p + 1 < NP) asm volatile("s_waitcnt vmcnt(4)" ::: "memory");
        else            asm volatile("s_waitcnt vmcnt(0)" ::: "memory");
        short8 af[4], wf[4];
        #pragma unroll
        for (int nt = 0; nt < 4; nt++)
            af[nt] = *(const short8*)(aT + aswz(nt * 16 + l16, p * 32 + q * 8));
        #pragma unroll
        for (int mt = 0; mt < 4; mt++)
            wf[mt] = *(const short8*)(wb + wrow + mt * 16 * 32);
        if (p + 2 < NP) {
            // ds_reads of wb must land in regs before re-staging wb
            asm volatile("s_waitcnt lgkmcnt(0)" ::: "memory");
            __builtin_amdgcn_sched_barrier(0);
            stage_panel(W, wstride, (p + 2) * 32, wb, wave, lane);
        }
        #pragma unroll
        for (int nt = 0; nt < 4; nt++)
            #pragma unroll
            for (int mt = 0; mt < 4; mt++)
                acc[nt][mt] = __builtin_amdgcn_mfma_f32_16x16x32_bf16(af[nt], wf[mt], acc[nt][mt], 0, 0, 0);
    }
}

__device__ __forceinline__ void epi_to_lds(f32x4 acc[4][4], const float* __restrict__ b,
                                           unsigned short* __restrict__ aT,
                                           int wave, int l16, int q)
{
    float bias[4];
    #pragma unroll
    for (int mt = 0; mt < 4; mt++) bias[mt] = b[wave * 64 + mt * 16 + l16];
    #pragma unroll
    for (int nt = 0; nt < 4; nt++)
        #pragma unroll
        for (int r = 0; r < 4; r++)
            #pragma unroll
            for (int mt = 0; mt < 4; mt++) {
                const int row = nt * 16 + q * 4 + r;         // C/D: row=quad*4+reg
                const int col = wave * 64 + mt * 16 + l16;   // C/D: col=lane&15
                aT[aswz(row, col)] = f2bf(lrelu(acc[nt][mt][r] + bias[mt]));
            }
}

__global__ __launch_bounds__(256) void fused_gemm_kernel(
                                  const unsigned short* __restrict__ aggHi,
                                  const unsigned short* __restrict__ aggLo,
                                  const unsigned short* __restrict__ xHi,
                                  const unsigned short* __restrict__ xLo,
                                  const unsigned short* __restrict__ Wg,
                                  const float* __restrict__ b_rel,
                                  const unsigned short* __restrict__ Wb1,
                                  const float* __restrict__ b_l1,
                                  const unsigned short* __restrict__ Wb2,
                                  const float* __restrict__ b_l2,
                                  const unsigned short* __restrict__ Wb3,
                                  const float* __restrict__ b_l3,
                                  const float* __restrict__ w_pred,
                                  const float* __restrict__ b_pred,
                                  float* __restrict__ out, int N)
{
    __shared__ __align__(16) unsigned short aT[64 * 256];     // 32 KB, XOR-swizzled
    __shared__ __align__(16) unsigned short sW[2][256 * 32];  // 32 KB W-panel dbuf
    const int t = threadIdx.x;
    const int n0 = blockIdx.x * 64;
    const int wave = t >> 6, lane = t & 63, q = lane >> 4, l16 = lane & 15;

    for (int u = t; u < 640; u += 256) {
        const int row = u / 10, c = (u % 10) * 4;
        const int srow = min(n0 + row, N - 1);
        const size_t off = (size_t)srow * 40 + c;
        *(ushort4*)(aT + aswz(row, c))       = *(const ushort4*)(aggHi + off);
        *(ushort4*)(aT + aswz(row, 40 + c))  = *(const ushort4*)(xHi + off);
        *(ushort4*)(aT + aswz(row, 80 + c))  = *(const ushort4*)(aggLo + off);
        *(ushort4*)(aT + aswz(row, 120 + c)) = *(const ushort4*)(xLo + off);
    }
    __syncthreads();

    {   // layer 0: graphconv, K=160
        f32x4 acc[4][4] = {};
        gemm_layer(aT, Wg, 160, 160, sW[0], sW[1], wave, lane, l16, q, acc);
        __syncthreads();
        epi_to_lds(acc, b_rel, aT, wave, l16, q);
        __syncthreads();
    }
    {   // layer 1
        f32x4 acc[4][4] = {};
        gemm_layer(aT, Wb1, 256, 256, sW[0], sW[1], wave, lane, l16, q, acc);
        __syncthreads();
        epi_to_lds(acc, b_l1, aT, wave, l16, q);
        __syncthreads();
    }
    {   // layer 2
        f32x4 acc[4][4] = {};
        gemm_layer(aT, Wb2, 256, 256, sW[0], sW[1], wave, lane, l16, q, acc);
        __syncthreads();
        epi_to_lds(acc, b_l2, aT, wave, l16, q);
        __syncthreads();
    }
    {   // layer 3 + pred epilogue (h3 never leaves registers)
        f32x4 acc[4][4] = {};
        gemm_layer(aT, Wb3, 256, 256, sW[0], sW[1], wave, lane, l16, q, acc);

        float bias[4], wp[4];
        #pragma unroll
        for (int mt = 0; mt < 4; mt++) {
            const int col = wave * 64 + mt * 16 + l16;
            bias[mt] = b_l3[col];
            wp[mt] = w_pred[col];
        }
        // partial sums go into the wave's PRIVATE sW chunk (sW dead now;
        // chunk privacy -> no barrier needed before the write)
        float* spw = (float*)(sW[0] + (wave * 4) * 512);
        #pragma unroll
        for (int nt = 0; nt < 4; nt++)
            #pragma unroll
            for (int r = 0; r < 4; r++) {
                float p = 0.f;
                #pragma unroll
                for (int mt = 0; mt < 4; mt++)
                    p += lrelu(acc[nt][mt][r] + bias[mt]) * wp[mt];
                p += __shfl_xor(p, 1);
                p += __shfl_xor(p, 2);
                p += __shfl_xor(p, 4);
                p += __shfl_xor(p, 8);
                if (l16 == 0) spw[nt * 16 + q * 4 + r] = p;
            }
        __syncthreads();

        if (t < 64) {
            const int row = n0 + t;
            if (row < N) {
                float s = b_pred[0];
                #pragma unroll
                for (int w = 0; w < 4; w++)
                    s += ((const float*)(sW[0] + (w * 4) * 512))[t];
                out[row] = s;
            }
        }
    }
}

// ---------------------------------------------------------------------------
extern "C" void kernel_launch(void* const* d_in, const int* in_sizes, int n_in,
                              void* d_out, int out_size, void* d_ws, size_t ws_size,
                              hipStream_t stream)
{
    const float* pose   = (const float*)d_in[0];
    const float* views  = (const float*)d_in[1];
    const int*   ei     = (const int*)d_in[2];
    const float* w_e1   = (const float*)d_in[3];
    const float* b_e1   = (const float*)d_in[4];
    const float* w_e2   = (const float*)d_in[5];
    const float* b_e2   = (const float*)d_in[6];
    const float* w_rel  = (const float*)d_in[7];
    const float* b_rel  = (const float*)d_in[8];
    const float* w_root = (const float*)d_in[9];
    const float* w_l1   = (const float*)d_in[10];
    const float* b_l1   = (const float*)d_in[11];
    const float* w_l2   = (const float*)d_in[12];
    const float* b_l2   = (const float*)d_in[13];
    const float* w_l3   = (const float*)d_in[14];
    const float* b_l3   = (const float*)d_in[15];
    const float* w_pred = (const float*)d_in[16];
    const float* b_pred = (const float*)d_in[17];
    float* out = (float*)d_out;

    const int N = in_sizes[0] / 3;        // 50000
    const int E = in_sizes[2] / 2;        // 4950000
    const int NB = (N + 63) >> 6;         // 782 buckets
    const int NBLK = (N + 63) / 64;       // 782 GEMM row blocks

    // Workspace layout (no sorted / node_start / node_cnt / h buffers)
    unsigned short* xHi = (unsigned short*)d_ws;     // N*40 bf16
    unsigned short* xLo = xHi + (size_t)N * 40;      // N*40 bf16
    unsigned short* aggHi = xLo + (size_t)N * 40;    // N*40 bf16
    unsigned short* aggLo = aggHi + (size_t)N * 40;  // N*40 bf16
    __half* xh = (__half*)(aggLo + (size_t)N * 40);  // (N+1)*40 fp16; row N = 0
    int* pairs = (int*)(xh + (size_t)(N + 1) * 40 + 24);   // NB*CAP ints
    int* gcur  = pairs + (size_t)NB * CAP;           // 1024
    unsigned short* Wb1 = (unsigned short*)(gcur + 1024);  // 256*256
    unsigned short* Wb2 = Wb1 + 256 * 256;
    unsigned short* Wb3 = Wb2 + 256 * 256;
    unsigned short* Wg  = Wb3 + 256 * 256;           // 256*160

    encoder_kernel<<<(N + 3) / 4, 256, 0, stream>>>(
        pose, views, w_e1, b_e1, w_e2, b_e2,
        w_l1, w_l2, w_l3, w_rel, w_root,
        Wb1, Wb2, Wb3, Wg, gcur, xHi, xLo, xh, N);

    bin_kernel<<<(E + EPB - 1) / EPB, 512, 0, stream>>>(ei, gcur, pairs, E, NB);

    sort_gather_kernel<<<NB, 512, 0, stream>>>(gcur, pairs, xh, aggHi, aggLo, N);

    fused_gemm_kernel<<<NBLK, 256, 0, stream>>>(
        aggHi, aggLo, xHi, xLo, Wg, b_rel,
        Wb1, b_l1, Wb2, b_l2, Wb3, b_l3,
        w_pred, b_pred, out, N);
}

// Round 7
// 326.889 us; speedup vs baseline: 1.0414x; 1.0001x over previous
//
#include <hip/hip_runtime.h>
#include <hip/hip_fp16.h>

#define NEG_SLOPE 0.1f
__device__ __forceinline__ float lrelu(float v) { return fmaxf(v, NEG_SLOPE * v); }

constexpr int CAP = 8704;   // per-bucket capacity (mean 6330 + 24-align pads); == 17*512
constexpr int EPB = 8192;   // edges per bin block (16 per thread, 512 threads)

typedef __attribute__((ext_vector_type(8))) short short8;   // 8 bf16 (4 VGPRs)
typedef __attribute__((ext_vector_type(4))) float f32x4;    // MFMA accum
typedef __attribute__((ext_vector_type(2))) float f32x2;    // packed v_pk_add_f32
typedef __attribute__((ext_vector_type(4))) int i32x4;      // clang vec (nontemporal-ok)

__device__ __forceinline__ unsigned short f2bf(float f) {   // RNE
    union { float f; unsigned u; } v; v.f = f;
    const unsigned r = v.u + 0x7FFF + ((v.u >> 16) & 1);
    return (unsigned short)(r >> 16);
}
__device__ __forceinline__ float bf2f(unsigned short h) {
    union { unsigned u; float f; } v; v.u = ((unsigned)h) << 16;
    return v.f;
}

// ---------------------------------------------------------------------------
// Encoder (+fused prep in blocks 0..255): 4 nodes per 256-thread block,
// 12 KB LDS (high occupancy — do NOT fuse with bin: its 60 KB LDS halves
// encoder occupancy, measured +22 µs in r13). Prep: bf16 weight conversions,
// Wg build, gcur zero, xh sentinel row.
// ---------------------------------------------------------------------------
__global__ __launch_bounds__(256) void encoder_kernel(
        const float* __restrict__ pose,
        const float* __restrict__ views,
        const float* __restrict__ w1, const float* __restrict__ b1,
        const float* __restrict__ w2, const float* __restrict__ b2,
        const float* __restrict__ w_l1, const float* __restrict__ w_l2,
        const float* __restrict__ w_l3, const float* __restrict__ w_rel,
        const float* __restrict__ w_root,
        unsigned short* __restrict__ Wb1, unsigned short* __restrict__ Wb2,
        unsigned short* __restrict__ Wb3, unsigned short* __restrict__ Wg,
        int* __restrict__ gcur,
        unsigned short* __restrict__ xHi, unsigned short* __restrict__ xLo,
        __half* __restrict__ xh, int N)
{
    __shared__ float s_w1[81];
    __shared__ float s_b1[9];
    __shared__ float s_w2[27];
    __shared__ float s_b2[1];
    __shared__ float s_c1[4][9][80];   // [lnode][oc][(p&1)*40 + (p>>1)]

    const int t = threadIdx.x;

    // fused prep (first 256 blocks); runs before bin in stream order
    if (blockIdx.x < 256) {
        const int i = blockIdx.x * 256 + t;
        Wb1[i] = f2bf(w_l1[i]);
        Wb2[i] = f2bf(w_l2[i]);
        Wb3[i] = f2bf(w_l3[i]);
        if (i < 40960) {   // Wg[256][160] = [w_rel|w_root|w_rel|w_root]
            const int m = i / 160, c = i % 160;
            const int k = c % 80;
            const float v = (k < 40) ? w_rel[m * 40 + k] : w_root[m * 40 + (k - 40)];
            Wg[i] = f2bf(v);
        }
        if (i < 1024) gcur[i] = 0;
        if (i < 40) xh[(size_t)N * 40 + i] = __float2half(0.f);
    }

    if (t < 81) s_w1[t] = w1[t];
    if (t >= 96 && t < 105) s_b1[t - 96] = b1[t - 96];
    if (t >= 128 && t < 155) s_w2[t - 128] = w2[t - 128];
    if (t == 240) s_b2[0] = b2[0];
    __syncthreads();

    const int nb = blockIdx.x * 4;

    // conv1: 300 flat (node,pos) tasks over 2 passes (pass 2: waves 1-3 execz)
    #pragma unroll
    for (int pass = 0; pass < 2; pass++) {
        const int task = pass * 256 + t;
        if (task < 300) {
            const int ln = task / 75;
            const int p  = task % 75;
            const int n  = min(nb + ln, N - 1);
            const float* __restrict__ vin = views + (size_t)n * 453 + 2 * p;
            float e[3], o[3], e1[3];
            #pragma unroll
            for (int ic = 0; ic < 3; ic++) {
                const float* ci = vin + ic * 151;
                e[ic] = ci[0]; o[ic] = ci[1]; e1[ic] = ci[2];
            }
            const int didx = (p & 1) * 40 + (p >> 1);
            #pragma unroll
            for (int oc = 0; oc < 9; oc++) {
                float v = s_b1[oc];
                #pragma unroll
                for (int ic = 0; ic < 3; ic++)
                    v += s_w1[oc * 9 + ic * 3 + 0] * e[ic]
                       + s_w1[oc * 9 + ic * 3 + 1] * o[ic]
                       + s_w1[oc * 9 + ic * 3 + 2] * e1[ic];
                s_c1[ln][oc][didx] = lrelu(v);
            }
        }
    }
    __syncthreads();

    // conv2 + pose passthrough: 160 flat tasks, coalesced stores
    if (t < 160) {
        const int ln = t / 40, f = t % 40;
        const int n  = min(nb + ln, N - 1);
        float outv;
        if (f < 3) {
            outv = pose[(size_t)n * 3 + f];
        } else {
            const int ow = f - 3;
            float v = s_b2[0];
            #pragma unroll
            for (int ic = 0; ic < 9; ic++)
                v += s_w2[ic * 3 + 0] * s_c1[ln][ic][ow]
                   + s_w2[ic * 3 + 1] * s_c1[ln][ic][40 + ow]
                   + s_w2[ic * 3 + 2] * s_c1[ln][ic][ow + 1];
            outv = lrelu(v);
        }
        const unsigned short hi = f2bf(outv);
        const unsigned short lo = f2bf(outv - bf2f(hi));
        xHi[(size_t)n * 40 + f] = hi;
        xLo[(size_t)n * 40 + f] = lo;
        xh[(size_t)n * 40 + f] = __float2half(outv);
    }
}

// ---------------------------------------------------------------------------
// Coarse binning (512 thr, 8192 edges/block): rank via LDS histogram, stage
// bucket-ordered in LDS, linear write-out. Packed entry = src*80 | dloc<<22.
// ---------------------------------------------------------------------------
__global__ __launch_bounds__(512) void bin_kernel(
        const int* __restrict__ ei, int* __restrict__ gcur,
        int* __restrict__ pairs, int E, int NB)
{
    __shared__ int s_hist[1024];
    __shared__ int s_loff[1024];
    __shared__ int s_base[1024];
    __shared__ int s_wave8[8];
    __shared__ int s_pk[EPB];                 // 32 KB
    __shared__ unsigned short s_bkt[EPB];     // 16 KB
    const int t = threadIdx.x;
    const int lane = t & 63, wid = t >> 6;    // 8 waves
    const int e0 = blockIdx.x * EPB + t * 16;
    const int tot = min(E - (int)blockIdx.x * EPB, EPB);

    for (int i = t; i < 1024; i += 512) s_hist[i] = 0;
    __syncthreads();

    int pk[16], mt[16];
    auto proc = [&](int j, int sv, int dv) {
        const int b = dv >> 6;
        const int r = atomicAdd(&s_hist[b], 1);
        pk[j] = sv * 80 | ((dv & 63) << 22);
        mt[j] = b | (r << 10);
    };

    if (e0 + 16 <= E) {
        #pragma unroll
        for (int q = 0; q < 4; q++) {
            const int4 sv = *(const int4*)(ei + e0 + 4 * q);
            const int4 dv = *(const int4*)(ei + E + e0 + 4 * q);
            proc(4 * q + 0, sv.x, dv.x);
            proc(4 * q + 1, sv.y, dv.y);
            proc(4 * q + 2, sv.z, dv.z);
            proc(4 * q + 3, sv.w, dv.w);
        }
    } else {
        #pragma unroll
        for (int j = 0; j < 16; j++) {
            mt[j] = -1;
            const int e = e0 + j;
            if (e < E) proc(j, ei[e], ei[E + e]);
        }
    }
    __syncthreads();

    // exclusive scan of s_hist[0..1023] -> s_loff
    int carry = 0;
    #pragma unroll
    for (int base = 0; base < 1024; base += 512) {
        const int i = base + t;
        const int v = s_hist[i];
        int sc = v;
        #pragma unroll
        for (int d = 1; d < 64; d <<= 1) {
            const int u = __shfl_up(sc, d);
            if (lane >= d) sc += u;
        }
        if (lane == 63) s_wave8[wid] = sc;
        __syncthreads();
        if (wid == 0) {
            int wv = (lane < 8) ? s_wave8[lane] : 0;
            #pragma unroll
            for (int d = 1; d < 8; d <<= 1) {
                const int u = __shfl_up(wv, d);
                if (lane >= d) wv += u;
            }
            if (lane < 8) s_wave8[lane] = wv;
        }
        __syncthreads();
        const int waveoff = (wid > 0) ? s_wave8[wid - 1] : 0;
        s_loff[i] = carry + waveoff + sc - v;
        const int chunk_tot = s_wave8[7];
        __syncthreads();
        carry += chunk_tot;
    }

    for (int i = t; i < NB; i += 512) {
        const int c = s_hist[i];
        if (c > 0) s_base[i] = atomicAdd(&gcur[i], c);
    }
    __syncthreads();

    #pragma unroll
    for (int j = 0; j < 16; j++) {
        if (mt[j] >= 0) {
            const int b = mt[j] & 1023;
            const int pos = s_loff[b] + (mt[j] >> 10);
            s_pk[pos] = pk[j];
            s_bkt[pos] = (unsigned short)b;
        }
    }
    __syncthreads();

    for (int i = t; i < tot; i += 512) {
        const int b = s_bkt[i];
        const int p = s_base[b] + (i - s_loff[b]);
        if (p < CAP) pairs[b * CAP + p] = s_pk[i];
    }
}

// ---------------------------------------------------------------------------
// FUSED per-bucket sort + gather (512 thr, one block per bucket): counting
// sort scatters byte-offset edges into an LDS sorted list (runs 24-aligned,
// sentinel N*80 = zero row), then 8 waves gather 8 nodes each.
// r2: 16 B/lane gather (12 slots x 5 lanes) — TA-address-bound fix, -8 µs.
// r6: (a) rank saved from phase-1 atomicAdd return -> phase-3 scatter is a
// plain LDS write (halves sort atomics, kills s_cur); (b) staging loads
// 17 dwords -> 4x dwordx4 + 1 dword (via clang ext-vector i32x4 — HIP int4
// is rejected by __builtin_nontemporal_load, r6 compile fail); (c) gather
// accumulators f32x2 -> v_pk_add_f32.
// ---------------------------------------------------------------------------
__global__ __launch_bounds__(512) void sort_gather_kernel(
        const int* __restrict__ gcur,
        const int* __restrict__ pairs,
        const __half* __restrict__ xh,
        unsigned short* __restrict__ aggHi,
        unsigned short* __restrict__ aggLo, int N)
{
    __shared__ int s_sorted[CAP];             // 34.8 KB
    __shared__ int s_cnt[64], s_off[64];
    const int b = blockIdx.x;
    const int t = threadIdx.x;
    const int cnt = min(gcur[b], CAP);
    const int* __restrict__ pr = pairs + (size_t)b * CAP;

    if (t < 64) s_cnt[t] = 0;

    // stage this thread's packed entries in registers (single global read,
    // 4x dwordx4 + 1 dword; sentinel -1 marks out-of-range slots)
    int pk[17];
    {
        const i32x4* __restrict__ pr4 = (const i32x4*)pr;
        #pragma unroll
        for (int j = 0; j < 4; j++) {
            const int m = t + j * 512;
            const i32x4 v = __builtin_nontemporal_load(pr4 + m);
            const int e0 = m * 4;
            pk[4 * j + 0] = (e0 + 0 < cnt) ? v.x : -1;
            pk[4 * j + 1] = (e0 + 1 < cnt) ? v.y : -1;
            pk[4 * j + 2] = (e0 + 2 < cnt) ? v.z : -1;
            pk[4 * j + 3] = (e0 + 3 < cnt) ? v.w : -1;
        }
        const int m16 = 8192 + t;
        pk[16] = (m16 < cnt) ? __builtin_nontemporal_load(pr + m16) : -1;
    }
    __syncthreads();

    // histogram; atomicAdd return value IS this edge's rank within its node
    int rk[17];
    #pragma unroll
    for (int j = 0; j < 17; j++)
        if (pk[j] >= 0) rk[j] = atomicAdd(&s_cnt[pk[j] >> 22], 1);
    __syncthreads();

    if (t < 64) {   // wave 0: exclusive scan of 24-aligned counts
        const int c = s_cnt[t];
        const int p = ((c + 23) / 24) * 24;
        int sc = p;
        #pragma unroll
        for (int d = 1; d < 64; d <<= 1) {
            const int u = __shfl_up(sc, d);
            if (t >= d) sc += u;
        }
        s_off[t] = sc - p;
    }
    __syncthreads();

    if (t < 64) {   // pad fill: sentinel byte offset N*80 (zero row in xh)
        const int e0 = s_off[t] + s_cnt[t];
        const int e1 = s_off[t] + ((s_cnt[t] + 23) / 24) * 24;
        for (int i = e0; i < e1 && i < CAP; i++) s_sorted[i] = N * 80;
    }
    #pragma unroll
    for (int j = 0; j < 17; j++) {
        if (pk[j] >= 0) {
            const int pos = s_off[pk[j] >> 22] + rk[j];   // no atomic
            if (pos < CAP) s_sorted[pos] = pk[j] & 0x3FFFFF;
        }
    }
    __syncthreads();

    // gather: wave w handles local nodes w*8 .. w*8+7.
    // 12 slots x 5 lanes; each lane loads 16 B (8 halfs) of its slot's row.
    const int wave = t >> 6, lane = t & 63;
    const int slot = min(lane / 5, 11);       // lanes 60..63 duplicate slot 11
    const int f8 = lane % 5;                  // feature octet (8 halfs = 16 B)
    const char* __restrict__ xb = (const char*)xh + f8 * 16;

    #pragma unroll 1
    for (int i = 0; i < 8; i++) {
        const int ln = wave * 8 + i;
        const int n = b * 64 + ln;
        if (n >= N) break;                    // wave-uniform
        const int c = s_cnt[ln];
        const int cntp = ((c + 23) / 24) * 24;
        const int* __restrict__ srt = s_sorted + s_off[ln] + slot;

        f32x2 a0 = {0.f, 0.f}, a1 = {0.f, 0.f}, a2 = {0.f, 0.f}, a3 = {0.f, 0.f};

        union { unsigned v; __half2 h; } cv;
        auto cv2 = [&](unsigned u) -> f32x2 {
            cv.v = u;
            const float2 ff = __half22float2(cv.h);
            f32x2 r; r.x = ff.x; r.y = ff.y; return r;
        };
        auto acc8 = [&](uint4 u) {
            a0 += cv2(u.x); a1 += cv2(u.y); a2 += cv2(u.z); a3 += cv2(u.w);
        };

        int e = 0;
        #pragma unroll 1
        for (; e + 48 <= cntp; e += 48) {     // 4 x 16B loads in flight
            const int o0 = srt[e];
            const int o1 = srt[e + 12];
            const int o2 = srt[e + 24];
            const int o3 = srt[e + 36];
            const uint4 u0 = *(const uint4*)(xb + o0);
            const uint4 u1 = *(const uint4*)(xb + o1);
            const uint4 u2 = *(const uint4*)(xb + o2);
            const uint4 u3 = *(const uint4*)(xb + o3);
            acc8(u0); acc8(u1); acc8(u2); acc8(u3);
        }
        if (e < cntp) {                       // tail: exactly one 24-chunk
            const int o0 = srt[e];
            const int o1 = srt[e + 12];
            const uint4 u0 = *(const uint4*)(xb + o0);
            const uint4 u1 = *(const uint4*)(xb + o1);
            acc8(u0); acc8(u1);
        }

        // fold 12 slots -> slot 0 (lanes 0..4); deltas preserve f8 (==0 mod 5)
        #pragma unroll
        for (int st = 0; st < 2; st++) {
            const int d = st ? 15 : 30;
            a0.x += __shfl(a0.x, lane + d); a0.y += __shfl(a0.y, lane + d);
            a1.x += __shfl(a1.x, lane + d); a1.y += __shfl(a1.y, lane + d);
            a2.x += __shfl(a2.x, lane + d); a2.y += __shfl(a2.y, lane + d);
            a3.x += __shfl(a3.x, lane + d); a3.y += __shfl(a3.y, lane + d);
        }
        a0.x += __shfl(a0.x, lane + 5) + __shfl(a0.x, lane + 10);
        a0.y += __shfl(a0.y, lane + 5) + __shfl(a0.y, lane + 10);
        a1.x += __shfl(a1.x, lane + 5) + __shfl(a1.x, lane + 10);
        a1.y += __shfl(a1.y, lane + 5) + __shfl(a1.y, lane + 10);
        a2.x += __shfl(a2.x, lane + 5) + __shfl(a2.x, lane + 10);
        a2.y += __shfl(a2.y, lane + 5) + __shfl(a2.y, lane + 10);
        a3.x += __shfl(a3.x, lane + 5) + __shfl(a3.x, lane + 10);
        a3.y += __shfl(a3.y, lane + 5) + __shfl(a3.y, lane + 10);

        if (lane < 5) {
            const float av[8] = {a0.x, a0.y, a1.x, a1.y, a2.x, a2.y, a3.x, a3.y};
            unsigned short h[8], l[8];
            #pragma unroll
            for (int j = 0; j < 8; j++) {
                h[j] = f2bf(av[j]);
                l[j] = f2bf(av[j] - bf2f(h[j]));
            }
            uint4 H, L;
            H.x = h[0] | ((unsigned)h[1] << 16); H.y = h[2] | ((unsigned)h[3] << 16);
            H.z = h[4] | ((unsigned)h[5] << 16); H.w = h[6] | ((unsigned)h[7] << 16);
            L.x = l[0] | ((unsigned)l[1] << 16); L.y = l[2] | ((unsigned)l[3] << 16);
            L.z = l[4] | ((unsigned)l[5] << 16); L.w = l[6] | ((unsigned)l[7] << 16);
            *(uint4*)(aggHi + (size_t)n * 40 + lane * 8) = H;
            *(uint4*)(aggLo + (size_t)n * 40 + lane * 8) = L;
        }
    }
}

// ---------------------------------------------------------------------------
// FUSED GEMM chain: graphconv (K=160) -> mlp1 -> mlp2 -> mlp3+pred, one
// block per 64 rows; h stays in LDS between layers.
// r5: W-panel LDS staging via async global_load_lds, double-buffered with
// counted vmcnt(4) (never 0 mid-loop). Each wave stages exactly the 64 W-rows
// it reads (chunk-private LDS) -> NO barriers in the k-loop; waves skew
// freely. wf latency 250cy L2 -> 12cy ds_read. aT re-laid at stride 256 with
// XOR swizzle col^((row&7)<<3); s_part folded into wave-private sW chunk ->
// LDS exactly 64 KB, 2 blocks/CU. (r4 lesson: no reg dbuf / min-waves bound.)
// ---------------------------------------------------------------------------
__device__ __forceinline__ int aswz(int row, int col) {   // aT swizzled ushort idx
    return row * 256 + (col ^ ((row & 7) << 3));
}

__device__ __forceinline__ void gload16(const void* g, void* l) {
    __builtin_amdgcn_global_load_lds(
        (const __attribute__((address_space(1))) unsigned int*)g,
        (__attribute__((address_space(3))) unsigned int*)l,
        16, 0, 0);
}

// stage the wave's own 64 rows of W[*, k0..k0+32) into its private chunks
__device__ __forceinline__ void stage_panel(const unsigned short* __restrict__ W,
                                            int wstride, int k0,
                                            unsigned short* buf, int wave, int lane)
{
    const int rbase = wave * 64 + (lane >> 2);
    const int cu = (lane & 3) * 8;
    #pragma unroll
    for (int j = 0; j < 4; j++) {
        const int row = rbase + j * 16;
        gload16(W + (size_t)row * wstride + k0 + cu,
                buf + (wave * 4 + j) * 512);
    }
}

__device__ __forceinline__ void gemm_layer(const unsigned short* __restrict__ aT,
                                           const unsigned short* __restrict__ W,
                                           int wstride, int K,
                                           unsigned short* __restrict__ sW0,
                                           unsigned short* __restrict__ sW1,
                                           int wave, int lane, int l16, int q,
                                           f32x4 acc[4][4])
{
    const int NP = K >> 5;                    // 32-wide k panels
    stage_panel(W, wstride, 0, sW0, wave, lane);
    stage_panel(W, wstride, 32, sW1, wave, lane);
    const int wrow = (wave * 64 + l16) * 32 + q * 8;

    for (int p = 0; p < NP; p++) {
        unsigned short* wb = (p & 1) ? sW1 : sW0;
        // counted wait: oldest 4 outstanding (panel p) done; panel p+1 in flight
        if (p + 1 < NP) asm volatile("s_waitcnt vmcnt(4)" ::: "memory");
        else            asm volatile("s_waitcnt vmcnt(0)" ::: "memory");
        short8 af[4], wf[4];
        #pragma unroll
        for (int nt = 0; nt < 4; nt++)
            af[nt] = *(const short8*)(aT + aswz(nt * 16 + l16, p * 32 + q * 8));
        #pragma unroll
        for (int mt = 0; mt < 4; mt++)
            wf[mt] = *(const short8*)(wb + wrow + mt * 16 * 32);
        if (p + 2 < NP) {
            // ds_reads of wb must land in regs before re-staging wb
            asm volatile("s_waitcnt lgkmcnt(0)" ::: "memory");
            __builtin_amdgcn_sched_barrier(0);
            stage_panel(W, wstride, (p + 2) * 32, wb, wave, lane);
        }
        #pragma unroll
        for (int nt = 0; nt < 4; nt++)
            #pragma unroll
            for (int mt = 0; mt < 4; mt++)
                acc[nt][mt] = __builtin_amdgcn_mfma_f32_16x16x32_bf16(af[nt], wf[mt], acc[nt][mt], 0, 0, 0);
    }
}

__device__ __forceinline__ void epi_to_lds(f32x4 acc[4][4], const float* __restrict__ b,
                                           unsigned short* __restrict__ aT,
                                           int wave, int l16, int q)
{
    float bias[4];
    #pragma unroll
    for (int mt = 0; mt < 4; mt++) bias[mt] = b[wave * 64 + mt * 16 + l16];
    #pragma unroll
    for (int nt = 0; nt < 4; nt++)
        #pragma unroll
        for (int r = 0; r < 4; r++)
            #pragma unroll
            for (int mt = 0; mt < 4; mt++) {
                const int row = nt * 16 + q * 4 + r;         // C/D: row=quad*4+reg
                const int col = wave * 64 + mt * 16 + l16;   // C/D: col=lane&15
                aT[aswz(row, col)] = f2bf(lrelu(acc[nt][mt][r] + bias[mt]));
            }
}

__global__ __launch_bounds__(256) void fused_gemm_kernel(
                                  const unsigned short* __restrict__ aggHi,
                                  const unsigned short* __restrict__ aggLo,
                                  const unsigned short* __restrict__ xHi,
                                  const unsigned short* __restrict__ xLo,
                                  const unsigned short* __restrict__ Wg,
                                  const float* __restrict__ b_rel,
                                  const unsigned short* __restrict__ Wb1,
                                  const float* __restrict__ b_l1,
                                  const unsigned short* __restrict__ Wb2,
                                  const float* __restrict__ b_l2,
                                  const unsigned short* __restrict__ Wb3,
                                  const float* __restrict__ b_l3,
                                  const float* __restrict__ w_pred,
                                  const float* __restrict__ b_pred,
                                  float* __restrict__ out, int N)
{
    __shared__ __align__(16) unsigned short aT[64 * 256];     // 32 KB, XOR-swizzled
    __shared__ __align__(16) unsigned short sW[2][256 * 32];  // 32 KB W-panel dbuf
    const int t = threadIdx.x;
    const int n0 = blockIdx.x * 64;
    const int wave = t >> 6, lane = t & 63, q = lane >> 4, l16 = lane & 15;

    for (int u = t; u < 640; u += 256) {
        const int row = u / 10, c = (u % 10) * 4;
        const int srow = min(n0 + row, N - 1);
        const size_t off = (size_t)srow * 40 + c;
        *(ushort4*)(aT + aswz(row, c))       = *(const ushort4*)(aggHi + off);
        *(ushort4*)(aT + aswz(row, 40 + c))  = *(const ushort4*)(xHi + off);
        *(ushort4*)(aT + aswz(row, 80 + c))  = *(const ushort4*)(aggLo + off);
        *(ushort4*)(aT + aswz(row, 120 + c)) = *(const ushort4*)(xLo + off);
    }
    __syncthreads();

    {   // layer 0: graphconv, K=160
        f32x4 acc[4][4] = {};
        gemm_layer(aT, Wg, 160, 160, sW[0], sW[1], wave, lane, l16, q, acc);
        __syncthreads();
        epi_to_lds(acc, b_rel, aT, wave, l16, q);
        __syncthreads();
    }
    {   // layer 1
        f32x4 acc[4][4] = {};
        gemm_layer(aT, Wb1, 256, 256, sW[0], sW[1], wave, lane, l16, q, acc);
        __syncthreads();
        epi_to_lds(acc, b_l1, aT, wave, l16, q);
        __syncthreads();
    }
    {   // layer 2
        f32x4 acc[4][4] = {};
        gemm_layer(aT, Wb2, 256, 256, sW[0], sW[1], wave, lane, l16, q, acc);
        __syncthreads();
        epi_to_lds(acc, b_l2, aT, wave, l16, q);
        __syncthreads();
    }
    {   // layer 3 + pred epilogue (h3 never leaves registers)
        f32x4 acc[4][4] = {};
        gemm_layer(aT, Wb3, 256, 256, sW[0], sW[1], wave, lane, l16, q, acc);

        float bias[4], wp[4];
        #pragma unroll
        for (int mt = 0; mt < 4; mt++) {
            const int col = wave * 64 + mt * 16 + l16;
            bias[mt] = b_l3[col];
            wp[mt] = w_pred[col];
        }
        // partial sums go into the wave's PRIVATE sW chunk (sW dead now;
        // chunk privacy -> no barrier needed before the write)
        float* spw = (float*)(sW[0] + (wave * 4) * 512);
        #pragma unroll
        for (int nt = 0; nt < 4; nt++)
            #pragma unroll
            for (int r = 0; r < 4; r++) {
                float p = 0.f;
                #pragma unroll
                for (int mt = 0; mt < 4; mt++)
                    p += lrelu(acc[nt][mt][r] + bias[mt]) * wp[mt];
                p += __shfl_xor(p, 1);
                p += __shfl_xor(p, 2);
                p += __shfl_xor(p, 4);
                p += __shfl_xor(p, 8);
                if (l16 == 0) spw[nt * 16 + q * 4 + r] = p;
            }
        __syncthreads();

        if (t < 64) {
            const int row = n0 + t;
            if (row < N) {
                float s = b_pred[0];
                #pragma unroll
                for (int w = 0; w < 4; w++)
                    s += ((const float*)(sW[0] + (w * 4) * 512))[t];
                out[row] = s;
            }
        }
    }
}

// ---------------------------------------------------------------------------
extern "C" void kernel_launch(void* const* d_in, const int* in_sizes, int n_in,
                              void* d_out, int out_size, void* d_ws, size_t ws_size,
                              hipStream_t stream)
{
    const float* pose   = (const float*)d_in[0];
    const float* views  = (const float*)d_in[1];
    const int*   ei     = (const int*)d_in[2];
    const float* w_e1   = (const float*)d_in[3];
    const float* b_e1   = (const float*)d_in[4];
    const float* w_e2   = (const float*)d_in[5];
    const float* b_e2   = (const float*)d_in[6];
    const float* w_rel  = (const float*)d_in[7];
    const float* b_rel  = (const float*)d_in[8];
    const float* w_root = (const float*)d_in[9];
    const float* w_l1   = (const float*)d_in[10];
    const float* b_l1   = (const float*)d_in[11];
    const float* w_l2   = (const float*)d_in[12];
    const float* b_l2   = (const float*)d_in[13];
    const float* w_l3   = (const float*)d_in[14];
    const float* b_l3   = (const float*)d_in[15];
    const float* w_pred = (const float*)d_in[16];
    const float* b_pred = (const float*)d_in[17];
    float* out = (float*)d_out;

    const int N = in_sizes[0] / 3;        // 50000
    const int E = in_sizes[2] / 2;        // 4950000
    const int NB = (N + 63) >> 6;         // 782 buckets
    const int NBLK = (N + 63) / 64;       // 782 GEMM row blocks

    // Workspace layout (no sorted / node_start / node_cnt / h buffers)
    unsigned short* xHi = (unsigned short*)d_ws;     // N*40 bf16
    unsigned short* xLo = xHi + (size_t)N * 40;      // N*40 bf16
    unsigned short* aggHi = xLo + (size_t)N * 40;    // N*40 bf16
    unsigned short* aggLo = aggHi + (size_t)N * 40;  // N*40 bf16
    __half* xh = (__half*)(aggLo + (size_t)N * 40);  // (N+1)*40 fp16; row N = 0
    int* pairs = (int*)(xh + (size_t)(N + 1) * 40 + 24);   // NB*CAP ints
    int* gcur  = pairs + (size_t)NB * CAP;           // 1024
    unsigned short* Wb1 = (unsigned short*)(gcur + 1024);  // 256*256
    unsigned short* Wb2 = Wb1 + 256 * 256;
    unsigned short* Wb3 = Wb2 + 256 * 256;
    unsigned short* Wg  = Wb3 + 256 * 256;           // 256*160

    encoder_kernel<<<(N + 3) / 4, 256, 0, stream>>>(
        pose, views, w_e1, b_e1, w_e2, b_e2,
        w_l1, w_l2, w_l3, w_rel, w_root,
        Wb1, Wb2, Wb3, Wg, gcur, xHi, xLo, xh, N);

    bin_kernel<<<(E + EPB - 1) / EPB, 512, 0, stream>>>(ei, gcur, pairs, E, NB);

    sort_gather_kernel<<<NB, 512, 0, stream>>>(gcur, pairs, xh, aggHi, aggLo, N);

    fused_gemm_kernel<<<NBLK, 256, 0, stream>>>(
        aggHi, aggLo, xHi, xLo, Wg, b_rel,
        Wb1, b_l1, Wb2, b_l2, Wb3, b_l3,
        w_pred, b_pred, out, N);
}

// Round 8
// 325.075 us; speedup vs baseline: 1.0472x; 1.0056x over previous
//
#include <hip/hip_runtime.h>
#include <hip/hip_fp16.h>

#define NEG_SLOPE 0.1f
__device__ __forceinline__ float lrelu(float v) { return fmaxf(v, NEG_SLOPE * v); }

constexpr int CAP = 8704;   // per-bucket capacity (mean 6330 + 24-align pads); == 17*512
constexpr int EPB = 8192;   // edges per bin block (16 per thread, 512 threads)

typedef __attribute__((ext_vector_type(8))) short short8;   // 8 bf16 (4 VGPRs)
typedef __attribute__((ext_vector_type(4))) float f32x4;    // MFMA accum
typedef __attribute__((ext_vector_type(2))) float f32x2;    // packed v_pk_add_f32
typedef __attribute__((ext_vector_type(4))) int i32x4;      // clang vec (nontemporal-ok)

__device__ __forceinline__ unsigned short f2bf(float f) {   // RNE
    union { float f; unsigned u; } v; v.f = f;
    const unsigned r = v.u + 0x7FFF + ((v.u >> 16) & 1);
    return (unsigned short)(r >> 16);
}
__device__ __forceinline__ float bf2f(unsigned short h) {
    union { unsigned u; float f; } v; v.u = ((unsigned)h) << 16;
    return v.f;
}

// ---------------------------------------------------------------------------
// Encoder (+fused prep in blocks 0..255). Unchanged from r7.
// ---------------------------------------------------------------------------
__global__ __launch_bounds__(256) void encoder_kernel(
        const float* __restrict__ pose,
        const float* __restrict__ views,
        const float* __restrict__ w1, const float* __restrict__ b1,
        const float* __restrict__ w2, const float* __restrict__ b2,
        const float* __restrict__ w_l1, const float* __restrict__ w_l2,
        const float* __restrict__ w_l3, const float* __restrict__ w_rel,
        const float* __restrict__ w_root,
        unsigned short* __restrict__ Wb1, unsigned short* __restrict__ Wb2,
        unsigned short* __restrict__ Wb3, unsigned short* __restrict__ Wg,
        int* __restrict__ gcur,
        unsigned short* __restrict__ xHi, unsigned short* __restrict__ xLo,
        __half* __restrict__ xh, int N)
{
    __shared__ float s_w1[81];
    __shared__ float s_b1[9];
    __shared__ float s_w2[27];
    __shared__ float s_b2[1];
    __shared__ float s_c1[4][9][80];   // [lnode][oc][(p&1)*40 + (p>>1)]

    const int t = threadIdx.x;

    if (blockIdx.x < 256) {
        const int i = blockIdx.x * 256 + t;
        Wb1[i] = f2bf(w_l1[i]);
        Wb2[i] = f2bf(w_l2[i]);
        Wb3[i] = f2bf(w_l3[i]);
        if (i < 40960) {   // Wg[256][160] = [w_rel|w_root|w_rel|w_root]
            const int m = i / 160, c = i % 160;
            const int k = c % 80;
            const float v = (k < 40) ? w_rel[m * 40 + k] : w_root[m * 40 + (k - 40)];
            Wg[i] = f2bf(v);
        }
        if (i < 1024) gcur[i] = 0;
        if (i < 40) xh[(size_t)N * 40 + i] = __float2half(0.f);
    }

    if (t < 81) s_w1[t] = w1[t];
    if (t >= 96 && t < 105) s_b1[t - 96] = b1[t - 96];
    if (t >= 128 && t < 155) s_w2[t - 128] = w2[t - 128];
    if (t == 240) s_b2[0] = b2[0];
    __syncthreads();

    const int nb = blockIdx.x * 4;

    #pragma unroll
    for (int pass = 0; pass < 2; pass++) {
        const int task = pass * 256 + t;
        if (task < 300) {
            const int ln = task / 75;
            const int p  = task % 75;
            const int n  = min(nb + ln, N - 1);
            const float* __restrict__ vin = views + (size_t)n * 453 + 2 * p;
            float e[3], o[3], e1[3];
            #pragma unroll
            for (int ic = 0; ic < 3; ic++) {
                const float* ci = vin + ic * 151;
                e[ic] = ci[0]; o[ic] = ci[1]; e1[ic] = ci[2];
            }
            const int didx = (p & 1) * 40 + (p >> 1);
            #pragma unroll
            for (int oc = 0; oc < 9; oc++) {
                float v = s_b1[oc];
                #pragma unroll
                for (int ic = 0; ic < 3; ic++)
                    v += s_w1[oc * 9 + ic * 3 + 0] * e[ic]
                       + s_w1[oc * 9 + ic * 3 + 1] * o[ic]
                       + s_w1[oc * 9 + ic * 3 + 2] * e1[ic];
                s_c1[ln][oc][didx] = lrelu(v);
            }
        }
    }
    __syncthreads();

    if (t < 160) {
        const int ln = t / 40, f = t % 40;
        const int n  = min(nb + ln, N - 1);
        float outv;
        if (f < 3) {
            outv = pose[(size_t)n * 3 + f];
        } else {
            const int ow = f - 3;
            float v = s_b2[0];
            #pragma unroll
            for (int ic = 0; ic < 9; ic++)
                v += s_w2[ic * 3 + 0] * s_c1[ln][ic][ow]
                   + s_w2[ic * 3 + 1] * s_c1[ln][ic][40 + ow]
                   + s_w2[ic * 3 + 2] * s_c1[ln][ic][ow + 1];
            outv = lrelu(v);
        }
        const unsigned short hi = f2bf(outv);
        const unsigned short lo = f2bf(outv - bf2f(hi));
        xHi[(size_t)n * 40 + f] = hi;
        xLo[(size_t)n * 40 + f] = lo;
        xh[(size_t)n * 40 + f] = __float2half(outv);
    }
}

// ---------------------------------------------------------------------------
// Coarse binning. r8 change: packed entry = src | dloc<<22 (src<50000 fits
// 16 bits — the fused kernel stores 16-bit ids in LDS to fit the 64 KB union).
// ---------------------------------------------------------------------------
__global__ __launch_bounds__(512) void bin_kernel(
        const int* __restrict__ ei, int* __restrict__ gcur,
        int* __restrict__ pairs, int E, int NB)
{
    __shared__ int s_hist[1024];
    __shared__ int s_loff[1024];
    __shared__ int s_base[1024];
    __shared__ int s_wave8[8];
    __shared__ int s_pk[EPB];                 // 32 KB
    __shared__ unsigned short s_bkt[EPB];     // 16 KB
    const int t = threadIdx.x;
    const int lane = t & 63, wid = t >> 6;    // 8 waves
    const int e0 = blockIdx.x * EPB + t * 16;
    const int tot = min(E - (int)blockIdx.x * EPB, EPB);

    for (int i = t; i < 1024; i += 512) s_hist[i] = 0;
    __syncthreads();

    int pk[16], mt[16];
    auto proc = [&](int j, int sv, int dv) {
        const int b = dv >> 6;
        const int r = atomicAdd(&s_hist[b], 1);
        pk[j] = sv | ((dv & 63) << 22);
        mt[j] = b | (r << 10);
    };

    if (e0 + 16 <= E) {
        #pragma unroll
        for (int q = 0; q < 4; q++) {
            const int4 sv = *(const int4*)(ei + e0 + 4 * q);
            const int4 dv = *(const int4*)(ei + E + e0 + 4 * q);
            proc(4 * q + 0, sv.x, dv.x);
            proc(4 * q + 1, sv.y, dv.y);
            proc(4 * q + 2, sv.z, dv.z);
            proc(4 * q + 3, sv.w, dv.w);
        }
    } else {
        #pragma unroll
        for (int j = 0; j < 16; j++) {
            mt[j] = -1;
            const int e = e0 + j;
            if (e < E) proc(j, ei[e], ei[E + e]);
        }
    }
    __syncthreads();

    // exclusive scan of s_hist[0..1023] -> s_loff
    int carry = 0;
    #pragma unroll
    for (int base = 0; base < 1024; base += 512) {
        const int i = base + t;
        const int v = s_hist[i];
        int sc = v;
        #pragma unroll
        for (int d = 1; d < 64; d <<= 1) {
            const int u = __shfl_up(sc, d);
            if (lane >= d) sc += u;
        }
        if (lane == 63) s_wave8[wid] = sc;
        __syncthreads();
        if (wid == 0) {
            int wv = (lane < 8) ? s_wave8[lane] : 0;
            #pragma unroll
            for (int d = 1; d < 8; d <<= 1) {
                const int u = __shfl_up(wv, d);
                if (lane >= d) wv += u;
            }
            if (lane < 8) s_wave8[lane] = wv;
        }
        __syncthreads();
        const int waveoff = (wid > 0) ? s_wave8[wid - 1] : 0;
        s_loff[i] = carry + waveoff + sc - v;
        const int chunk_tot = s_wave8[7];
        __syncthreads();
        carry += chunk_tot;
    }

    for (int i = t; i < NB; i += 512) {
        const int c = s_hist[i];
        if (c > 0) s_base[i] = atomicAdd(&gcur[i], c);
    }
    __syncthreads();

    #pragma unroll
    for (int j = 0; j < 16; j++) {
        if (mt[j] >= 0) {
            const int b = mt[j] & 1023;
            const int pos = s_loff[b] + (mt[j] >> 10);
            s_pk[pos] = pk[j];
            s_bkt[pos] = (unsigned short)b;
        }
    }
    __syncthreads();

    for (int i = t; i < tot; i += 512) {
        const int b = s_bkt[i];
        const int p = s_base[b] + (i - s_loff[b]);
        if (p < CAP) pairs[b * CAP + p] = s_pk[i];
    }
}

// ---------------------------------------------------------------------------
// r8 FUSED sort + gather + GEMM chain (512 thr, one block per 64-node bucket
// == one GEMM row block). Gather writes straight into the aT LDS tile (no
// aggHi/aggLo global round-trip); sort scratch (16-bit-id s_sorted + cnt/off)
// UNIONs with the W-panel double-buffer (sort state dead before GEMM).
// LDS = 32 KB aT + 32 KB union = 64 KB -> 2 blocks/CU; gather-phase blocks
// overlap GEMM-phase blocks on the CU (VALU/TA vs MFMA pipes).
// GEMM: 8 waves x 32 output cols (acc[4][2]); W staging chunk-private,
// barrier-free, counted vmcnt(2).
// ---------------------------------------------------------------------------
__device__ __forceinline__ int aswz(int row, int col) {   // aT swizzled ushort idx
    return row * 256 + (col ^ ((row & 7) << 3));
}

__device__ __forceinline__ void gload16(const void* g, void* l) {
    __builtin_amdgcn_global_load_lds(
        (const __attribute__((address_space(1))) unsigned int*)g,
        (__attribute__((address_space(3))) unsigned int*)l,
        16, 0, 0);
}

// stage the wave's own 32 rows of W[*, k0..k0+32) into its 2 private chunks
__device__ __forceinline__ void stage_panel(const unsigned short* __restrict__ W,
                                            int wstride, int k0,
                                            unsigned short* buf, int wave, int lane)
{
    const int rbase = wave * 32 + (lane >> 2);
    const int cu = (lane & 3) * 8;
    #pragma unroll
    for (int j = 0; j < 2; j++) {
        const int row = rbase + j * 16;
        gload16(W + (size_t)row * wstride + k0 + cu,
                buf + (wave * 2 + j) * 512);
    }
}

__device__ __forceinline__ void gemm_layer(const unsigned short* __restrict__ aT,
                                           const unsigned short* __restrict__ W,
                                           int wstride, int K,
                                           unsigned short* __restrict__ sWb,
                                           int wave, int lane, int l16, int q,
                                           f32x4 acc[4][2])
{
    const int NP = K >> 5;                    // 32-wide k panels
    stage_panel(W, wstride, 0,  sWb,        wave, lane);
    stage_panel(W, wstride, 32, sWb + 8192, wave, lane);
    const int wro = (wave * 2) * 512 + l16 * 32 + q * 8;

    for (int p = 0; p < NP; p++) {
        unsigned short* wb = sWb + (p & 1) * 8192;
        // counted wait: panel p's 2 loads done; panel p+1's 2 stay in flight
        if (p + 1 < NP) asm volatile("s_waitcnt vmcnt(2)" ::: "memory");
        else            asm volatile("s_waitcnt vmcnt(0)" ::: "memory");
        short8 af[4], wf[2];
        #pragma unroll
        for (int nt = 0; nt < 4; nt++)
            af[nt] = *(const short8*)(aT + aswz(nt * 16 + l16, p * 32 + q * 8));
        #pragma unroll
        for (int mt = 0; mt < 2; mt++)
            wf[mt] = *(const short8*)(wb + wro + mt * 512);
        if (p + 2 < NP) {
            // ds_reads of wb must land in regs before re-staging wb
            asm volatile("s_waitcnt lgkmcnt(0)" ::: "memory");
            __builtin_amdgcn_sched_barrier(0);
            stage_panel(W, wstride, (p + 2) * 32, wb, wave, lane);
        }
        #pragma unroll
        for (int nt = 0; nt < 4; nt++)
            #pragma unroll
            for (int mt = 0; mt < 2; mt++)
                acc[nt][mt] = __builtin_amdgcn_mfma_f32_16x16x32_bf16(af[nt], wf[mt], acc[nt][mt], 0, 0, 0);
    }
}

__device__ __forceinline__ void epi_to_lds(f32x4 acc[4][2], const float* __restrict__ b,
                                           unsigned short* __restrict__ aT,
                                           int wave, int l16, int q)
{
    float bias[2];
    #pragma unroll
    for (int mt = 0; mt < 2; mt++) bias[mt] = b[wave * 32 + mt * 16 + l16];
    #pragma unroll
    for (int nt = 0; nt < 4; nt++)
        #pragma unroll
        for (int r = 0; r < 4; r++)
            #pragma unroll
            for (int mt = 0; mt < 2; mt++) {
                const int row = nt * 16 + q * 4 + r;         // C/D: row=quad*4+reg
                const int col = wave * 32 + mt * 16 + l16;   // C/D: col=lane&15
                aT[aswz(row, col)] = f2bf(lrelu(acc[nt][mt][r] + bias[mt]));
            }
}

__global__ __launch_bounds__(512) void sg_gemm_kernel(
        const int* __restrict__ gcur,
        const int* __restrict__ pairs,
        const __half* __restrict__ xh,
        const unsigned short* __restrict__ xHi,
        const unsigned short* __restrict__ xLo,
        const unsigned short* __restrict__ Wg,
        const float* __restrict__ b_rel,
        const unsigned short* __restrict__ Wb1,
        const float* __restrict__ b_l1,
        const unsigned short* __restrict__ Wb2,
        const float* __restrict__ b_l2,
        const unsigned short* __restrict__ Wb3,
        const float* __restrict__ b_l3,
        const float* __restrict__ w_pred,
        const float* __restrict__ b_pred,
        float* __restrict__ out, int N)
{
    __shared__ __align__(16) unsigned short aT[64 * 256];   // 32 KB, XOR-swizzled
    __shared__ __align__(16) char uni[32768];               // sort scratch / sW dbuf
    unsigned short* s_sorted = (unsigned short*)uni;        // [CAP] 16-bit ids
    int* s_cnt = (int*)(uni + 17408);                       // [64]
    int* s_off = (int*)(uni + 17664);                       // [64]
    unsigned short* sWb = (unsigned short*)uni;             // GEMM phase view

    const int b = blockIdx.x;
    const int t = threadIdx.x;
    const int n0 = b * 64;
    const int wave = t >> 6, lane = t & 63, q = lane >> 4, l16 = lane & 15;
    const int cnt = min(gcur[b], CAP);
    const int* __restrict__ pr = pairs + (size_t)b * CAP;

    if (t < 64) s_cnt[t] = 0;

    // phase A: stage packed entries in regs + load x strips into aT
    int pk[17];
    {
        const i32x4* __restrict__ pr4 = (const i32x4*)pr;
        #pragma unroll
        for (int j = 0; j < 4; j++) {
            const int m = t + j * 512;
            const i32x4 v = __builtin_nontemporal_load(pr4 + m);
            const int e0 = m * 4;
            pk[4 * j + 0] = (e0 + 0 < cnt) ? v.x : -1;
            pk[4 * j + 1] = (e0 + 1 < cnt) ? v.y : -1;
            pk[4 * j + 2] = (e0 + 2 < cnt) ? v.z : -1;
            pk[4 * j + 3] = (e0 + 3 < cnt) ? v.w : -1;
        }
        const int m16 = 8192 + t;
        pk[16] = (m16 < cnt) ? __builtin_nontemporal_load(pr + m16) : -1;
    }
    for (int u = t; u < 640; u += 512) {      // xHi/xLo -> aT cols 40..79/120..159
        const int row = u / 10, c = (u % 10) * 4;
        const int srow = min(n0 + row, N - 1);
        const size_t off = (size_t)srow * 40 + c;
        *(ushort4*)(aT + aswz(row, 40 + c))  = *(const ushort4*)(xHi + off);
        *(ushort4*)(aT + aswz(row, 120 + c)) = *(const ushort4*)(xLo + off);
    }
    __syncthreads();

    // phase B: histogram; atomicAdd return IS the edge's rank within its node
    int rk[17];
    #pragma unroll
    for (int j = 0; j < 17; j++)
        if (pk[j] >= 0) rk[j] = atomicAdd(&s_cnt[pk[j] >> 22], 1);
    __syncthreads();

    if (t < 64) {   // phase C: wave 0 exclusive scan of 24-aligned counts
        const int c = s_cnt[t];
        const int p = ((c + 23) / 24) * 24;
        int sc = p;
        #pragma unroll
        for (int d = 1; d < 64; d <<= 1) {
            const int u = __shfl_up(sc, d);
            if (t >= d) sc += u;
        }
        s_off[t] = sc - p;
    }
    __syncthreads();

    if (t < 64) {   // pad fill: sentinel id N (zero row in xh)
        const int e0 = s_off[t] + s_cnt[t];
        const int e1 = s_off[t] + ((s_cnt[t] + 23) / 24) * 24;
        for (int i = e0; i < e1 && i < CAP; i++) s_sorted[i] = (unsigned short)N;
    }
    #pragma unroll
    for (int j = 0; j < 17; j++) {            // phase D: rank-addressed scatter
        if (pk[j] >= 0) {
            const int pos = s_off[pk[j] >> 22] + rk[j];
            if (pos < CAP) s_sorted[pos] = (unsigned short)(pk[j] & 0xFFFF);
        }
    }
    __syncthreads();

    // phase E: gather. wave w handles local nodes w*8..w*8+7;
    // 12 slots x 5 lanes, 16 B/lane; result written into aT cols 0..39/80..119.
    {
        const int slot = min(lane / 5, 11);
        const int f8 = lane % 5;
        const char* __restrict__ xb = (const char*)xh + f8 * 16;

        #pragma unroll 1
        for (int i = 0; i < 8; i++) {
            const int ln = wave * 8 + i;
            const int n = n0 + ln;
            if (n >= N) break;                // wave-uniform
            const int c = s_cnt[ln];
            const int cntp = ((c + 23) / 24) * 24;
            const unsigned short* __restrict__ srt = s_sorted + s_off[ln] + slot;

            f32x2 a0 = {0.f, 0.f}, a1 = {0.f, 0.f}, a2 = {0.f, 0.f}, a3 = {0.f, 0.f};
            union { unsigned v; __half2 h; } cv;
            auto cv2 = [&](unsigned u) -> f32x2 {
                cv.v = u;
                const float2 ff = __half22float2(cv.h);
                f32x2 r; r.x = ff.x; r.y = ff.y; return r;
            };
            auto acc8 = [&](uint4 u) {
                a0 += cv2(u.x); a1 += cv2(u.y); a2 += cv2(u.z); a3 += cv2(u.w);
            };

            int e = 0;
            #pragma unroll 1
            for (; e + 48 <= cntp; e += 48) {
                const int o0 = srt[e] * 80;
                const int o1 = srt[e + 12] * 80;
                const int o2 = srt[e + 24] * 80;
                const int o3 = srt[e + 36] * 80;
                const uint4 u0 = *(const uint4*)(xb + o0);
                const uint4 u1 = *(const uint4*)(xb + o1);
                const uint4 u2 = *(const uint4*)(xb + o2);
                const uint4 u3 = *(const uint4*)(xb + o3);
                acc8(u0); acc8(u1); acc8(u2); acc8(u3);
            }
            if (e < cntp) {                   // tail: exactly one 24-chunk
                const int o0 = srt[e] * 80;
                const int o1 = srt[e + 12] * 80;
                const uint4 u0 = *(const uint4*)(xb + o0);
                const uint4 u1 = *(const uint4*)(xb + o1);
                acc8(u0); acc8(u1);
            }

            #pragma unroll
            for (int st = 0; st < 2; st++) {  // fold 12 slots -> slot 0
                const int d = st ? 15 : 30;
                a0.x += __shfl(a0.x, lane + d); a0.y += __shfl(a0.y, lane + d);
                a1.x += __shfl(a1.x, lane + d); a1.y += __shfl(a1.y, lane + d);
                a2.x += __shfl(a2.x, lane + d); a2.y += __shfl(a2.y, lane + d);
                a3.x += __shfl(a3.x, lane + d); a3.y += __shfl(a3.y, lane + d);
            }
            a0.x += __shfl(a0.x, lane + 5) + __shfl(a0.x, lane + 10);
            a0.y += __shfl(a0.y, lane + 5) + __shfl(a0.y, lane + 10);
            a1.x += __shfl(a1.x, lane + 5) + __shfl(a1.x, lane + 10);
            a1.y += __shfl(a1.y, lane + 5) + __shfl(a1.y, lane + 10);
            a2.x += __shfl(a2.x, lane + 5) + __shfl(a2.x, lane + 10);
            a2.y += __shfl(a2.y, lane + 5) + __shfl(a2.y, lane + 10);
            a3.x += __shfl(a3.x, lane + 5) + __shfl(a3.x, lane + 10);
            a3.y += __shfl(a3.y, lane + 5) + __shfl(a3.y, lane + 10);

            if (lane < 5) {                   // direct LDS write into aT
                const float av[8] = {a0.x, a0.y, a1.x, a1.y, a2.x, a2.y, a3.x, a3.y};
                unsigned short h[8], l[8];
                #pragma unroll
                for (int j = 0; j < 8; j++) {
                    h[j] = f2bf(av[j]);
                    l[j] = f2bf(av[j] - bf2f(h[j]));
                }
                uint4 H, L;
                H.x = h[0] | ((unsigned)h[1] << 16); H.y = h[2] | ((unsigned)h[3] << 16);
                H.z = h[4] | ((unsigned)h[5] << 16); H.w = h[6] | ((unsigned)h[7] << 16);
                L.x = l[0] | ((unsigned)l[1] << 16); L.y = l[2] | ((unsigned)l[3] << 16);
                L.z = l[4] | ((unsigned)l[5] << 16); L.w = l[6] | ((unsigned)l[7] << 16);
                *(uint4*)(aT + aswz(ln, lane * 8))      = H;
                *(uint4*)(aT + aswz(ln, 80 + lane * 8)) = L;
            }
        }
    }
    __syncthreads();   // sort state dead; uni becomes the W-panel dbuf

    // phase F: GEMM chain
    {   // layer 0: graphconv, K=160
        f32x4 acc[4][2] = {};
        gemm_layer(aT, Wg, 160, 160, sWb, wave, lane, l16, q, acc);
        __syncthreads();
        epi_to_lds(acc, b_rel, aT, wave, l16, q);
        __syncthreads();
    }
    {   // layer 1
        f32x4 acc[4][2] = {};
        gemm_layer(aT, Wb1, 256, 256, sWb, wave, lane, l16, q, acc);
        __syncthreads();
        epi_to_lds(acc, b_l1, aT, wave, l16, q);
        __syncthreads();
    }
    {   // layer 2
        f32x4 acc[4][2] = {};
        gemm_layer(aT, Wb2, 256, 256, sWb, wave, lane, l16, q, acc);
        __syncthreads();
        epi_to_lds(acc, b_l2, aT, wave, l16, q);
        __syncthreads();
    }
    {   // layer 3 + pred epilogue (h3 never leaves registers)
        f32x4 acc[4][2] = {};
        gemm_layer(aT, Wb3, 256, 256, sWb, wave, lane, l16, q, acc);

        float bias[2], wp[2];
        #pragma unroll
        for (int mt = 0; mt < 2; mt++) {
            const int col = wave * 32 + mt * 16 + l16;
            bias[mt] = b_l3[col];
            wp[mt] = w_pred[col];
        }
        // partials into the wave's PRIVATE sW chunk (its own panel-0 bytes)
        float* spw = (float*)(uni + wave * 2048);
        #pragma unroll
        for (int nt = 0; nt < 4; nt++)
            #pragma unroll
            for (int r = 0; r < 4; r++) {
                float p = 0.f;
                #pragma unroll
                for (int mt = 0; mt < 2; mt++)
                    p += lrelu(acc[nt][mt][r] + bias[mt]) * wp[mt];
                p += __shfl_xor(p, 1);
                p += __shfl_xor(p, 2);
                p += __shfl_xor(p, 4);
                p += __shfl_xor(p, 8);
                if (l16 == 0) spw[nt * 16 + q * 4 + r] = p;
            }
        __syncthreads();

        if (t < 64) {
            const int row = n0 + t;
            if (row < N) {
                float s = b_pred[0];
                #pragma unroll
                for (int w = 0; w < 8; w++)
                    s += ((const float*)(uni + w * 2048))[t];
                out[row] = s;
            }
        }
    }
}

// ---------------------------------------------------------------------------
extern "C" void kernel_launch(void* const* d_in, const int* in_sizes, int n_in,
                              void* d_out, int out_size, void* d_ws, size_t ws_size,
                              hipStream_t stream)
{
    const float* pose   = (const float*)d_in[0];
    const float* views  = (const float*)d_in[1];
    const int*   ei     = (const int*)d_in[2];
    const float* w_e1   = (const float*)d_in[3];
    const float* b_e1   = (const float*)d_in[4];
    const float* w_e2   = (const float*)d_in[5];
    const float* b_e2   = (const float*)d_in[6];
    const float* w_rel  = (const float*)d_in[7];
    const float* b_rel  = (const float*)d_in[8];
    const float* w_root = (const float*)d_in[9];
    const float* w_l1   = (const float*)d_in[10];
    const float* b_l1   = (const float*)d_in[11];
    const float* w_l2   = (const float*)d_in[12];
    const float* b_l2   = (const float*)d_in[13];
    const float* w_l3   = (const float*)d_in[14];
    const float* b_l3   = (const float*)d_in[15];
    const float* w_pred = (const float*)d_in[16];
    const float* b_pred = (const float*)d_in[17];
    float* out = (float*)d_out;

    const int N = in_sizes[0] / 3;        // 50000
    const int E = in_sizes[2] / 2;        // 4950000
    const int NB = (N + 63) >> 6;         // 782 buckets == GEMM row blocks

    // Workspace layout (agg buffers eliminated by the r8 fusion)
    unsigned short* xHi = (unsigned short*)d_ws;     // N*40 bf16
    unsigned short* xLo = xHi + (size_t)N * 40;      // N*40 bf16
    __half* xh = (__half*)(xLo + (size_t)N * 40);    // (N+1)*40 fp16; row N = 0
    int* pairs = (int*)(xh + (size_t)(N + 1) * 40 + 24);   // NB*CAP ints
    int* gcur  = pairs + (size_t)NB * CAP;           // 1024
    unsigned short* Wb1 = (unsigned short*)(gcur + 1024);  // 256*256
    unsigned short* Wb2 = Wb1 + 256 * 256;
    unsigned short* Wb3 = Wb2 + 256 * 256;
    unsigned short* Wg  = Wb3 + 256 * 256;           // 256*160

    encoder_kernel<<<(N + 3) / 4, 256, 0, stream>>>(
        pose, views, w_e1, b_e1, w_e2, b_e2,
        w_l1, w_l2, w_l3, w_rel, w_root,
        Wb1, Wb2, Wb3, Wg, gcur, xHi, xLo, xh, N);

    bin_kernel<<<(E + EPB - 1) / EPB, 512, 0, stream>>>(ei, gcur, pairs, E, NB);

    sg_gemm_kernel<<<NB, 512, 0, stream>>>(
        gcur, pairs, xh, xHi, xLo, Wg, b_rel,
        Wb1, b_l1, Wb2, b_l2, Wb3, b_l3,
        w_pred, b_pred, out, N);
}

// Round 9
// 323.407 us; speedup vs baseline: 1.0526x; 1.0052x over previous
//
#include <hip/hip_runtime.h>
#include <hip/hip_fp16.h>

#define NEG_SLOPE 0.1f
__device__ __forceinline__ float lrelu(float v) { return fmaxf(v, NEG_SLOPE * v); }

constexpr int CAP = 8704;   // per-bucket capacity (mean 6330 + 24-align pads); == 17*512
constexpr int EPB = 8192;   // edges per bin block (16 per thread, 512 threads)

typedef __attribute__((ext_vector_type(8))) short short8;   // 8 bf16 (4 VGPRs)
typedef __attribute__((ext_vector_type(4))) float f32x4;    // MFMA accum
typedef __attribute__((ext_vector_type(2))) float f32x2;    // packed v_pk_add_f32
typedef __attribute__((ext_vector_type(4))) int i32x4;      // clang vec (nontemporal-ok)

__device__ __forceinline__ unsigned short f2bf(float f) {   // RNE
    union { float f; unsigned u; } v; v.f = f;
    const unsigned r = v.u + 0x7FFF + ((v.u >> 16) & 1);
    return (unsigned short)(r >> 16);
}
__device__ __forceinline__ float bf2f(unsigned short h) {
    union { unsigned u; float f; } v; v.u = ((unsigned)h) << 16;
    return v.f;
}

// ---------------------------------------------------------------------------
// Encoder (+fused prep in blocks 0..255). Unchanged from r8.
// ---------------------------------------------------------------------------
__global__ __launch_bounds__(256) void encoder_kernel(
        const float* __restrict__ pose,
        const float* __restrict__ views,
        const float* __restrict__ w1, const float* __restrict__ b1,
        const float* __restrict__ w2, const float* __restrict__ b2,
        const float* __restrict__ w_l1, const float* __restrict__ w_l2,
        const float* __restrict__ w_l3, const float* __restrict__ w_rel,
        const float* __restrict__ w_root,
        unsigned short* __restrict__ Wb1, unsigned short* __restrict__ Wb2,
        unsigned short* __restrict__ Wb3, unsigned short* __restrict__ Wg,
        int* __restrict__ gcur,
        unsigned short* __restrict__ xHi, unsigned short* __restrict__ xLo,
        __half* __restrict__ xh, int N)
{
    __shared__ float s_w1[81];
    __shared__ float s_b1[9];
    __shared__ float s_w2[27];
    __shared__ float s_b2[1];
    __shared__ float s_c1[4][9][80];   // [lnode][oc][(p&1)*40 + (p>>1)]

    const int t = threadIdx.x;

    if (blockIdx.x < 256) {
        const int i = blockIdx.x * 256 + t;
        Wb1[i] = f2bf(w_l1[i]);
        Wb2[i] = f2bf(w_l2[i]);
        Wb3[i] = f2bf(w_l3[i]);
        if (i < 40960) {   // Wg[256][160] = [w_rel|w_root|w_rel|w_root]
            const int m = i / 160, c = i % 160;
            const int k = c % 80;
            const float v = (k < 40) ? w_rel[m * 40 + k] : w_root[m * 40 + (k - 40)];
            Wg[i] = f2bf(v);
        }
        if (i < 1024) gcur[i] = 0;
        if (i < 40) xh[(size_t)N * 40 + i] = __float2half(0.f);
    }

    if (t < 81) s_w1[t] = w1[t];
    if (t >= 96 && t < 105) s_b1[t - 96] = b1[t - 96];
    if (t >= 128 && t < 155) s_w2[t - 128] = w2[t - 128];
    if (t == 240) s_b2[0] = b2[0];
    __syncthreads();

    const int nb = blockIdx.x * 4;

    #pragma unroll
    for (int pass = 0; pass < 2; pass++) {
        const int task = pass * 256 + t;
        if (task < 300) {
            const int ln = task / 75;
            const int p  = task % 75;
            const int n  = min(nb + ln, N - 1);
            const float* __restrict__ vin = views + (size_t)n * 453 + 2 * p;
            float e[3], o[3], e1[3];
            #pragma unroll
            for (int ic = 0; ic < 3; ic++) {
                const float* ci = vin + ic * 151;
                e[ic] = ci[0]; o[ic] = ci[1]; e1[ic] = ci[2];
            }
            const int didx = (p & 1) * 40 + (p >> 1);
            #pragma unroll
            for (int oc = 0; oc < 9; oc++) {
                float v = s_b1[oc];
                #pragma unroll
                for (int ic = 0; ic < 3; ic++)
                    v += s_w1[oc * 9 + ic * 3 + 0] * e[ic]
                       + s_w1[oc * 9 + ic * 3 + 1] * o[ic]
                       + s_w1[oc * 9 + ic * 3 + 2] * e1[ic];
                s_c1[ln][oc][didx] = lrelu(v);
            }
        }
    }
    __syncthreads();

    if (t < 160) {
        const int ln = t / 40, f = t % 40;
        const int n  = min(nb + ln, N - 1);
        float outv;
        if (f < 3) {
            outv = pose[(size_t)n * 3 + f];
        } else {
            const int ow = f - 3;
            float v = s_b2[0];
            #pragma unroll
            for (int ic = 0; ic < 9; ic++)
                v += s_w2[ic * 3 + 0] * s_c1[ln][ic][ow]
                   + s_w2[ic * 3 + 1] * s_c1[ln][ic][40 + ow]
                   + s_w2[ic * 3 + 2] * s_c1[ln][ic][ow + 1];
            outv = lrelu(v);
        }
        const unsigned short hi = f2bf(outv);
        const unsigned short lo = f2bf(outv - bf2f(hi));
        xHi[(size_t)n * 40 + f] = hi;
        xLo[(size_t)n * 40 + f] = lo;
        xh[(size_t)n * 40 + f] = __float2half(outv);
    }
}

// ---------------------------------------------------------------------------
// Coarse binning. Packed entry = src | dloc<<22 (src < 2^16). Unchanged.
// ---------------------------------------------------------------------------
__global__ __launch_bounds__(512) void bin_kernel(
        const int* __restrict__ ei, int* __restrict__ gcur,
        int* __restrict__ pairs, int E, int NB)
{
    __shared__ int s_hist[1024];
    __shared__ int s_loff[1024];
    __shared__ int s_base[1024];
    __shared__ int s_wave8[8];
    __shared__ int s_pk[EPB];                 // 32 KB
    __shared__ unsigned short s_bkt[EPB];     // 16 KB
    const int t = threadIdx.x;
    const int lane = t & 63, wid = t >> 6;    // 8 waves
    const int e0 = blockIdx.x * EPB + t * 16;
    const int tot = min(E - (int)blockIdx.x * EPB, EPB);

    for (int i = t; i < 1024; i += 512) s_hist[i] = 0;
    __syncthreads();

    int pk[16], mt[16];
    auto proc = [&](int j, int sv, int dv) {
        const int b = dv >> 6;
        const int r = atomicAdd(&s_hist[b], 1);
        pk[j] = sv | ((dv & 63) << 22);
        mt[j] = b | (r << 10);
    };

    if (e0 + 16 <= E) {
        #pragma unroll
        for (int q = 0; q < 4; q++) {
            const int4 sv = *(const int4*)(ei + e0 + 4 * q);
            const int4 dv = *(const int4*)(ei + E + e0 + 4 * q);
            proc(4 * q + 0, sv.x, dv.x);
            proc(4 * q + 1, sv.y, dv.y);
            proc(4 * q + 2, sv.z, dv.z);
            proc(4 * q + 3, sv.w, dv.w);
        }
    } else {
        #pragma unroll
        for (int j = 0; j < 16; j++) {
            mt[j] = -1;
            const int e = e0 + j;
            if (e < E) proc(j, ei[e], ei[E + e]);
        }
    }
    __syncthreads();

    // exclusive scan of s_hist[0..1023] -> s_loff
    int carry = 0;
    #pragma unroll
    for (int base = 0; base < 1024; base += 512) {
        const int i = base + t;
        const int v = s_hist[i];
        int sc = v;
        #pragma unroll
        for (int d = 1; d < 64; d <<= 1) {
            const int u = __shfl_up(sc, d);
            if (lane >= d) sc += u;
        }
        if (lane == 63) s_wave8[wid] = sc;
        __syncthreads();
        if (wid == 0) {
            int wv = (lane < 8) ? s_wave8[lane] : 0;
            #pragma unroll
            for (int d = 1; d < 8; d <<= 1) {
                const int u = __shfl_up(wv, d);
                if (lane >= d) wv += u;
            }
            if (lane < 8) s_wave8[lane] = wv;
        }
        __syncthreads();
        const int waveoff = (wid > 0) ? s_wave8[wid - 1] : 0;
        s_loff[i] = carry + waveoff + sc - v;
        const int chunk_tot = s_wave8[7];
        __syncthreads();
        carry += chunk_tot;
    }

    for (int i = t; i < NB; i += 512) {
        const int c = s_hist[i];
        if (c > 0) s_base[i] = atomicAdd(&gcur[i], c);
    }
    __syncthreads();

    #pragma unroll
    for (int j = 0; j < 16; j++) {
        if (mt[j] >= 0) {
            const int b = mt[j] & 1023;
            const int pos = s_loff[b] + (mt[j] >> 10);
            s_pk[pos] = pk[j];
            s_bkt[pos] = (unsigned short)b;
        }
    }
    __syncthreads();

    for (int i = t; i < tot; i += 512) {
        const int b = s_bkt[i];
        const int p = s_base[b] + (i - s_loff[b]);
        if (p < CAP) pairs[b * CAP + p] = s_pk[i];
    }
}

// ---------------------------------------------------------------------------
// r8 FUSED sort + gather + GEMM chain. r9 change: W-panel LDS layout swizzled
// to kill the 8-way bank conflict on wf ds_read_b128 (64B row stride put all
// 16 l16-lanes on 2 bank-quads; SQ_LDS_BANK_CONFLICT 5.33M). Per rule #21:
// LDS dest of global_load_lds stays LINEAR; the global SOURCE col-group is
// pre-swizzled (lane loads colgrp (lane&3)^((lane>>3)&3)) and the READ offset
// applies the same involution (q ^ ((l16>>1)&3)) -> 2-way (free).
// ---------------------------------------------------------------------------
__device__ __forceinline__ int aswz(int row, int col) {   // aT swizzled ushort idx
    return row * 256 + (col ^ ((row & 7) << 3));
}

__device__ __forceinline__ void gload16(const void* g, void* l) {
    __builtin_amdgcn_global_load_lds(
        (const __attribute__((address_space(1))) unsigned int*)g,
        (__attribute__((address_space(3))) unsigned int*)l,
        16, 0, 0);
}

// stage the wave's own 32 rows of W[*, k0..k0+32) into its 2 private chunks;
// global source col-group pre-swizzled so reads are conflict-free (r9)
__device__ __forceinline__ void stage_panel(const unsigned short* __restrict__ W,
                                            int wstride, int k0,
                                            unsigned short* buf, int wave, int lane)
{
    const int rbase = wave * 32 + (lane >> 2);
    const int cu = (((lane & 3) ^ ((lane >> 3) & 3))) * 8;   // r9 swizzled source
    #pragma unroll
    for (int j = 0; j < 2; j++) {
        const int row = rbase + j * 16;
        gload16(W + (size_t)row * wstride + k0 + cu,
                buf + (wave * 2 + j) * 512);
    }
}

__device__ __forceinline__ void gemm_layer(const unsigned short* __restrict__ aT,
                                           const unsigned short* __restrict__ W,
                                           int wstride, int K,
                                           unsigned short* __restrict__ sWb,
                                           int wave, int lane, int l16, int q,
                                           f32x4 acc[4][2])
{
    const int NP = K >> 5;                    // 32-wide k panels
    stage_panel(W, wstride, 0,  sWb,        wave, lane);
    stage_panel(W, wstride, 32, sWb + 8192, wave, lane);
    // r9: read slot = q ^ ((l16>>1)&3) — matches the staged source swizzle
    const int wro = (wave * 2) * 512 + l16 * 32 + (q ^ ((l16 >> 1) & 3)) * 8;

    for (int p = 0; p < NP; p++) {
        unsigned short* wb = sWb + (p & 1) * 8192;
        // counted wait: panel p's 2 loads done; panel p+1's 2 stay in flight
        if (p + 1 < NP) asm volatile("s_waitcnt vmcnt(2)" ::: "memory");
        else            asm volatile("s_waitcnt vmcnt(0)" ::: "memory");
        short8 af[4], wf[2];
        #pragma unroll
        for (int nt = 0; nt < 4; nt++)
            af[nt] = *(const short8*)(aT + aswz(nt * 16 + l16, p * 32 + q * 8));
        #pragma unroll
        for (int mt = 0; mt < 2; mt++)
            wf[mt] = *(const short8*)(wb + wro + mt * 512);
        if (p + 2 < NP) {
            // ds_reads of wb must land in regs before re-staging wb
            asm volatile("s_waitcnt lgkmcnt(0)" ::: "memory");
            __builtin_amdgcn_sched_barrier(0);
            stage_panel(W, wstride, (p + 2) * 32, wb, wave, lane);
        }
        #pragma unroll
        for (int nt = 0; nt < 4; nt++)
            #pragma unroll
            for (int mt = 0; mt < 2; mt++)
                acc[nt][mt] = __builtin_amdgcn_mfma_f32_16x16x32_bf16(af[nt], wf[mt], acc[nt][mt], 0, 0, 0);
    }
}

__device__ __forceinline__ void epi_to_lds(f32x4 acc[4][2], const float* __restrict__ b,
                                           unsigned short* __restrict__ aT,
                                           int wave, int l16, int q)
{
    float bias[2];
    #pragma unroll
    for (int mt = 0; mt < 2; mt++) bias[mt] = b[wave * 32 + mt * 16 + l16];
    #pragma unroll
    for (int nt = 0; nt < 4; nt++)
        #pragma unroll
        for (int r = 0; r < 4; r++)
            #pragma unroll
            for (int mt = 0; mt < 2; mt++) {
                const int row = nt * 16 + q * 4 + r;         // C/D: row=quad*4+reg
                const int col = wave * 32 + mt * 16 + l16;   // C/D: col=lane&15
                aT[aswz(row, col)] = f2bf(lrelu(acc[nt][mt][r] + bias[mt]));
            }
}

__global__ __launch_bounds__(512) void sg_gemm_kernel(
        const int* __restrict__ gcur,
        const int* __restrict__ pairs,
        const __half* __restrict__ xh,
        const unsigned short* __restrict__ xHi,
        const unsigned short* __restrict__ xLo,
        const unsigned short* __restrict__ Wg,
        const float* __restrict__ b_rel,
        const unsigned short* __restrict__ Wb1,
        const float* __restrict__ b_l1,
        const unsigned short* __restrict__ Wb2,
        const float* __restrict__ b_l2,
        const unsigned short* __restrict__ Wb3,
        const float* __restrict__ b_l3,
        const float* __restrict__ w_pred,
        const float* __restrict__ b_pred,
        float* __restrict__ out, int N)
{
    __shared__ __align__(16) unsigned short aT[64 * 256];   // 32 KB, XOR-swizzled
    __shared__ __align__(16) char uni[32768];               // sort scratch / sW dbuf
    unsigned short* s_sorted = (unsigned short*)uni;        // [CAP] 16-bit ids
    int* s_cnt = (int*)(uni + 17408);                       // [64]
    int* s_off = (int*)(uni + 17664);                       // [64]
    unsigned short* sWb = (unsigned short*)uni;             // GEMM phase view

    const int b = blockIdx.x;
    const int t = threadIdx.x;
    const int n0 = b * 64;
    const int wave = t >> 6, lane = t & 63, q = lane >> 4, l16 = lane & 15;
    const int cnt = min(gcur[b], CAP);
    const int* __restrict__ pr = pairs + (size_t)b * CAP;

    if (t < 64) s_cnt[t] = 0;

    // phase A: stage packed entries in regs + load x strips into aT
    int pk[17];
    {
        const i32x4* __restrict__ pr4 = (const i32x4*)pr;
        #pragma unroll
        for (int j = 0; j < 4; j++) {
            const int m = t + j * 512;
            const i32x4 v = __builtin_nontemporal_load(pr4 + m);
            const int e0 = m * 4;
            pk[4 * j + 0] = (e0 + 0 < cnt) ? v.x : -1;
            pk[4 * j + 1] = (e0 + 1 < cnt) ? v.y : -1;
            pk[4 * j + 2] = (e0 + 2 < cnt) ? v.z : -1;
            pk[4 * j + 3] = (e0 + 3 < cnt) ? v.w : -1;
        }
        const int m16 = 8192 + t;
        pk[16] = (m16 < cnt) ? __builtin_nontemporal_load(pr + m16) : -1;
    }
    for (int u = t; u < 640; u += 512) {      // xHi/xLo -> aT cols 40..79/120..159
        const int row = u / 10, c = (u % 10) * 4;
        const int srow = min(n0 + row, N - 1);
        const size_t off = (size_t)srow * 40 + c;
        *(ushort4*)(aT + aswz(row, 40 + c))  = *(const ushort4*)(xHi + off);
        *(ushort4*)(aT + aswz(row, 120 + c)) = *(const ushort4*)(xLo + off);
    }
    __syncthreads();

    // phase B: histogram; atomicAdd return IS the edge's rank within its node
    int rk[17];
    #pragma unroll
    for (int j = 0; j < 17; j++)
        if (pk[j] >= 0) rk[j] = atomicAdd(&s_cnt[pk[j] >> 22], 1);
    __syncthreads();

    if (t < 64) {   // phase C: wave 0 exclusive scan of 24-aligned counts
        const int c = s_cnt[t];
        const int p = ((c + 23) / 24) * 24;
        int sc = p;
        #pragma unroll
        for (int d = 1; d < 64; d <<= 1) {
            const int u = __shfl_up(sc, d);
            if (t >= d) sc += u;
        }
        s_off[t] = sc - p;
    }
    __syncthreads();

    if (t < 64) {   // pad fill: sentinel id N (zero row in xh)
        const int e0 = s_off[t] + s_cnt[t];
        const int e1 = s_off[t] + ((s_cnt[t] + 23) / 24) * 24;
        for (int i = e0; i < e1 && i < CAP; i++) s_sorted[i] = (unsigned short)N;
    }
    #pragma unroll
    for (int j = 0; j < 17; j++) {            // phase D: rank-addressed scatter
        if (pk[j] >= 0) {
            const int pos = s_off[pk[j] >> 22] + rk[j];
            if (pos < CAP) s_sorted[pos] = (unsigned short)(pk[j] & 0xFFFF);
        }
    }
    __syncthreads();

    // phase E: gather. wave w handles local nodes w*8..w*8+7;
    // 12 slots x 5 lanes, 16 B/lane; result written into aT cols 0..39/80..119.
    {
        const int slot = min(lane / 5, 11);
        const int f8 = lane % 5;
        const char* __restrict__ xb = (const char*)xh + f8 * 16;

        #pragma unroll 1
        for (int i = 0; i < 8; i++) {
            const int ln = wave * 8 + i;
            const int n = n0 + ln;
            if (n >= N) break;                // wave-uniform
            const int c = s_cnt[ln];
            const int cntp = ((c + 23) / 24) * 24;
            const unsigned short* __restrict__ srt = s_sorted + s_off[ln] + slot;

            f32x2 a0 = {0.f, 0.f}, a1 = {0.f, 0.f}, a2 = {0.f, 0.f}, a3 = {0.f, 0.f};
            union { unsigned v; __half2 h; } cv;
            auto cv2 = [&](unsigned u) -> f32x2 {
                cv.v = u;
                const float2 ff = __half22float2(cv.h);
                f32x2 r; r.x = ff.x; r.y = ff.y; return r;
            };
            auto acc8 = [&](uint4 u) {
                a0 += cv2(u.x); a1 += cv2(u.y); a2 += cv2(u.z); a3 += cv2(u.w);
            };

            int e = 0;
            #pragma unroll 1
            for (; e + 48 <= cntp; e += 48) {
                const int o0 = srt[e] * 80;
                const int o1 = srt[e + 12] * 80;
                const int o2 = srt[e + 24] * 80;
                const int o3 = srt[e + 36] * 80;
                const uint4 u0 = *(const uint4*)(xb + o0);
                const uint4 u1 = *(const uint4*)(xb + o1);
                const uint4 u2 = *(const uint4*)(xb + o2);
                const uint4 u3 = *(const uint4*)(xb + o3);
                acc8(u0); acc8(u1); acc8(u2); acc8(u3);
            }
            if (e < cntp) {                   // tail: exactly one 24-chunk
                const int o0 = srt[e] * 80;
                const int o1 = srt[e + 12] * 80;
                const uint4 u0 = *(const uint4*)(xb + o0);
                const uint4 u1 = *(const uint4*)(xb + o1);
                acc8(u0); acc8(u1);
            }

            #pragma unroll
            for (int st = 0; st < 2; st++) {  // fold 12 slots -> slot 0
                const int d = st ? 15 : 30;
                a0.x += __shfl(a0.x, lane + d); a0.y += __shfl(a0.y, lane + d);
                a1.x += __shfl(a1.x, lane + d); a1.y += __shfl(a1.y, lane + d);
                a2.x += __shfl(a2.x, lane + d); a2.y += __shfl(a2.y, lane + d);
                a3.x += __shfl(a3.x, lane + d); a3.y += __shfl(a3.y, lane + d);
            }
            a0.x += __shfl(a0.x, lane + 5) + __shfl(a0.x, lane + 10);
            a0.y += __shfl(a0.y, lane + 5) + __shfl(a0.y, lane + 10);
            a1.x += __shfl(a1.x, lane + 5) + __shfl(a1.x, lane + 10);
            a1.y += __shfl(a1.y, lane + 5) + __shfl(a1.y, lane + 10);
            a2.x += __shfl(a2.x, lane + 5) + __shfl(a2.x, lane + 10);
            a2.y += __shfl(a2.y, lane + 5) + __shfl(a2.y, lane + 10);
            a3.x += __shfl(a3.x, lane + 5) + __shfl(a3.x, lane + 10);
            a3.y += __shfl(a3.y, lane + 5) + __shfl(a3.y, lane + 10);

            if (lane < 5) {                   // direct LDS write into aT
                const float av[8] = {a0.x, a0.y, a1.x, a1.y, a2.x, a2.y, a3.x, a3.y};
                unsigned short h[8], l[8];
                #pragma unroll
                for (int j = 0; j < 8; j++) {
                    h[j] = f2bf(av[j]);
                    l[j] = f2bf(av[j] - bf2f(h[j]));
                }
                uint4 H, L;
                H.x = h[0] | ((unsigned)h[1] << 16); H.y = h[2] | ((unsigned)h[3] << 16);
                H.z = h[4] | ((unsigned)h[5] << 16); H.w = h[6] | ((unsigned)h[7] << 16);
                L.x = l[0] | ((unsigned)l[1] << 16); L.y = l[2] | ((unsigned)l[3] << 16);
                L.z = l[4] | ((unsigned)l[5] << 16); L.w = l[6] | ((unsigned)l[7] << 16);
                *(uint4*)(aT + aswz(ln, lane * 8))      = H;
                *(uint4*)(aT + aswz(ln, 80 + lane * 8)) = L;
            }
        }
    }
    __syncthreads();   // sort state dead; uni becomes the W-panel dbuf

    // phase F: GEMM chain
    {   // layer 0: graphconv, K=160
        f32x4 acc[4][2] = {};
        gemm_layer(aT, Wg, 160, 160, sWb, wave, lane, l16, q, acc);
        __syncthreads();
        epi_to_lds(acc, b_rel, aT, wave, l16, q);
        __syncthreads();
    }
    {   // layer 1
        f32x4 acc[4][2] = {};
        gemm_layer(aT, Wb1, 256, 256, sWb, wave, lane, l16, q, acc);
        __syncthreads();
        epi_to_lds(acc, b_l1, aT, wave, l16, q);
        __syncthreads();
    }
    {   // layer 2
        f32x4 acc[4][2] = {};
        gemm_layer(aT, Wb2, 256, 256, sWb, wave, lane, l16, q, acc);
        __syncthreads();
        epi_to_lds(acc, b_l2, aT, wave, l16, q);
        __syncthreads();
    }
    {   // layer 3 + pred epilogue (h3 never leaves registers)
        f32x4 acc[4][2] = {};
        gemm_layer(aT, Wb3, 256, 256, sWb, wave, lane, l16, q, acc);

        float bias[2], wp[2];
        #pragma unroll
        for (int mt = 0; mt < 2; mt++) {
            const int col = wave * 32 + mt * 16 + l16;
            bias[mt] = b_l3[col];
            wp[mt] = w_pred[col];
        }
        // partials into the wave's PRIVATE sW chunk (its own panel-0 bytes)
        float* spw = (float*)(uni + wave * 2048);
        #pragma unroll
        for (int nt = 0; nt < 4; nt++)
            #pragma unroll
            for (int r = 0; r < 4; r++) {
                float p = 0.f;
                #pragma unroll
                for (int mt = 0; mt < 2; mt++)
                    p += lrelu(acc[nt][mt][r] + bias[mt]) * wp[mt];
                p += __shfl_xor(p, 1);
                p += __shfl_xor(p, 2);
                p += __shfl_xor(p, 4);
                p += __shfl_xor(p, 8);
                if (l16 == 0) spw[nt * 16 + q * 4 + r] = p;
            }
        __syncthreads();

        if (t < 64) {
            const int row = n0 + t;
            if (row < N) {
                float s = b_pred[0];
                #pragma unroll
                for (int w = 0; w < 8; w++)
                    s += ((const float*)(uni + w * 2048))[t];
                out[row] = s;
            }
        }
    }
}

// ---------------------------------------------------------------------------
extern "C" void kernel_launch(void* const* d_in, const int* in_sizes, int n_in,
                              void* d_out, int out_size, void* d_ws, size_t ws_size,
                              hipStream_t stream)
{
    const float* pose   = (const float*)d_in[0];
    const float* views  = (const float*)d_in[1];
    const int*   ei     = (const int*)d_in[2];
    const float* w_e1   = (const float*)d_in[3];
    const float* b_e1   = (const float*)d_in[4];
    const float* w_e2   = (const float*)d_in[5];
    const float* b_e2   = (const float*)d_in[6];
    const float* w_rel  = (const float*)d_in[7];
    const float* b_rel  = (const float*)d_in[8];
    const float* w_root = (const float*)d_in[9];
    const float* w_l1   = (const float*)d_in[10];
    const float* b_l1   = (const float*)d_in[11];
    const float* w_l2   = (const float*)d_in[12];
    const float* b_l2   = (const float*)d_in[13];
    const float* w_l3   = (const float*)d_in[14];
    const float* b_l3   = (const float*)d_in[15];
    const float* w_pred = (const float*)d_in[16];
    const float* b_pred = (const float*)d_in[17];
    float* out = (float*)d_out;

    const int N = in_sizes[0] / 3;        // 50000
    const int E = in_sizes[2] / 2;        // 4950000
    const int NB = (N + 63) >> 6;         // 782 buckets == GEMM row blocks

    // Workspace layout (agg buffers eliminated by the r8 fusion)
    unsigned short* xHi = (unsigned short*)d_ws;     // N*40 bf16
    unsigned short* xLo = xHi + (size_t)N * 40;      // N*40 bf16
    __half* xh = (__half*)(xLo + (size_t)N * 40);    // (N+1)*40 fp16; row N = 0
    int* pairs = (int*)(xh + (size_t)(N + 1) * 40 + 24);   // NB*CAP ints
    int* gcur  = pairs + (size_t)NB * CAP;           // 1024
    unsigned short* Wb1 = (unsigned short*)(gcur + 1024);  // 256*256
    unsigned short* Wb2 = Wb1 + 256 * 256;
    unsigned short* Wb3 = Wb2 + 256 * 256;
    unsigned short* Wg  = Wb3 + 256 * 256;           // 256*160

    encoder_kernel<<<(N + 3) / 4, 256, 0, stream>>>(
        pose, views, w_e1, b_e1, w_e2, b_e2,
        w_l1, w_l2, w_l3, w_rel, w_root,
        Wb1, Wb2, Wb3, Wg, gcur, xHi, xLo, xh, N);

    bin_kernel<<<(E + EPB - 1) / EPB, 512, 0, stream>>>(ei, gcur, pairs, E, NB);

    sg_gemm_kernel<<<NB, 512, 0, stream>>>(
        gcur, pairs, xh, xHi, xLo, Wg, b_rel,
        Wb1, b_l1, Wb2, b_l2, Wb3, b_l3,
        w_pred, b_pred, out, N);
}